// Round 7
// baseline (857.366 us; speedup 1.0000x reference)
//
#include <hip/hip_runtime.h>
#include <hip/hip_bf16.h>

// MoEFSCIL: B=16, H=W=16, L=256, DIM=768, NH=8, HD=96, NEXP=8, TOPK=2.
// fp32 in/out. Big GEMMs bf16 MFMA; attention fp32; scan = two-pass
// segmented (8 segs/chain -> 48 waves/CU) with LDS direction-merge.

#define LTOK 256
#define DIMC 768

typedef unsigned short ushortt;
typedef __attribute__((ext_vector_type(8))) short bf16x8;
typedef __attribute__((ext_vector_type(4))) float f32x4;

__device__ __forceinline__ ushortt f2b(float f) {
  union { float f; unsigned u; } c; c.f = f;
  unsigned r = (c.u + 0x7FFFu + ((c.u >> 16) & 1u)) >> 16;
  return (ushortt)r;
}

// ---------------------------------------------------------------------------
// Fused 4-tensor fp32->bf16 cast (x, sa_in_w, sa_out_w, ca_in_w[:768] rows).
// ---------------------------------------------------------------------------
__global__ __launch_bounds__(256) void mk_mcast4(
    const float* __restrict__ s0, ushortt* __restrict__ d0,
    const float* __restrict__ s1, ushortt* __restrict__ d1,
    const float* __restrict__ s2, ushortt* __restrict__ d2,
    const float* __restrict__ s3, ushortt* __restrict__ d3)
{
  long g = (long)blockIdx.x * 256 + threadIdx.x;   // float4 chunk id
  const float* s; ushortt* dst; long o;
  if (g < 786432)       { s = s0; dst = d0; o = g; }
  else if (g < 1228800) { s = s1; dst = d1; o = g - 786432; }
  else if (g < 1376256) { s = s2; dst = d2; o = g - 1228800; }
  else                  { s = s3; dst = d3; o = g - 1376256; }
  o <<= 2;
  float4 v = *(const float4*)(s + o);
  ushort4 w;
  w.x = f2b(v.x); w.y = f2b(v.y); w.z = f2b(v.z); w.w = f2b(v.w);
  *(ushort4*)(dst + o) = w;
}

__global__ __launch_bounds__(256) void mk_cast(const float* __restrict__ in,
                                               ushortt* __restrict__ outp, long n)
{
  long i = ((long)blockIdx.x * 256 + threadIdx.x) * 4;
  if (i + 3 < n) {
    float4 v = *(const float4*)(in + i);
    ushort4 o;
    o.x = f2b(v.x); o.y = f2b(v.y); o.z = f2b(v.z); o.w = f2b(v.w);
    *(ushort4*)(outp + i) = o;
  }
}

// ---------------------------------------------------------------------------
// bf16 MFMA GEMM: C[z] = A[z](M,K) @ B[z](N,K)^T + bias.
// outBf: write bf16. Column-split: gcol<splitN -> C (ldc), else C2 (ldc2),
// both share coff stride sC. pairExp => MoE mode.
// ---------------------------------------------------------------------------
__global__ __launch_bounds__(256) void mk_mfma(
    const ushortt* __restrict__ A, const ushortt* __restrict__ B,
    const float* __restrict__ bias, void* __restrict__ C,
    int K, int lda, int ldb, int ldc,
    long sA, long sB, long sC, long sBias,
    const int* __restrict__ pairExp, int tilesN,
    int outBf, int splitN, void* __restrict__ C2, int ldc2)
{
  int z = blockIdx.y;
  long aoff = 0, boff = 0, coff = 0, biasoff = 0;
  if (pairExp) {
    int e = pairExp[z];
    aoff = (long)(z >> 1) * sA; boff = (long)e * sB;
    coff = (long)z * sC; biasoff = (long)e * sBias;
  }
  int tile = blockIdx.x;
  int tm = tile / tilesN, tn = tile - tm * tilesN;
  long m0 = (long)tm << 7, n0 = (long)tn << 7;

  __shared__ ushortt As[128][40];
  __shared__ ushortt Bs[128][40];

  int tid = threadIdx.x;
  int lane = tid & 63, wvi = tid >> 6;
  int wr = wvi >> 1, wc = wvi & 1;
  int lm = lane & 15, lg = lane >> 4;

  f32x4 zero4 = {0.f, 0.f, 0.f, 0.f};
  f32x4 acc[4][4];
#pragma unroll
  for (int i = 0; i < 4; i++)
#pragma unroll
    for (int j = 0; j < 4; j++) acc[i][j] = zero4;

  const ushortt* Ab = A + aoff;
  const ushortt* Bb = B + boff;

  for (int k0 = 0; k0 < K; k0 += 32) {
#pragma unroll
    for (int h = 0; h < 2; h++) {
      int q = tid + h * 256;
      int row = q >> 2, ck = (q & 3) << 3;
      *(uint4*)&As[row][ck] = *(const uint4*)(Ab + (m0 + row) * lda + k0 + ck);
      *(uint4*)&Bs[row][ck] = *(const uint4*)(Bb + (n0 + row) * ldb + k0 + ck);
    }
    __syncthreads();
    bf16x8 af[4], bfr[4];
#pragma unroll
    for (int i = 0; i < 4; i++)
      af[i] = *(const bf16x8*)&As[wr * 64 + i * 16 + lm][lg << 3];
#pragma unroll
    for (int j = 0; j < 4; j++)
      bfr[j] = *(const bf16x8*)&Bs[wc * 64 + j * 16 + lm][lg << 3];
#pragma unroll
    for (int i = 0; i < 4; i++)
#pragma unroll
      for (int j = 0; j < 4; j++)
        acc[i][j] = __builtin_amdgcn_mfma_f32_16x16x32_bf16(af[i], bfr[j], acc[i][j], 0, 0, 0);
    __syncthreads();
  }

#pragma unroll
  for (int mt = 0; mt < 4; mt++) {
#pragma unroll
    for (int nt = 0; nt < 4; nt++) {
      long grow = m0 + wr * 64 + mt * 16 + lg * 4;
      long gcol = n0 + wc * 64 + nt * 16 + lm;
      float bv = bias ? bias[biasoff + gcol] : 0.f;
      void* Ct; long col; int ld;
      if ((int)gcol < splitN) { Ct = C; col = gcol; ld = ldc; }
      else { Ct = C2; col = gcol - splitN; ld = ldc2; }
#pragma unroll
      for (int r = 0; r < 4; r++) {
        float v = acc[mt][nt][r] + bv;
        long idx = coff + (grow + r) * ld + col;
        if (outBf) ((ushortt*)Ct)[idx] = f2b(v);
        else ((float*)Ct)[idx] = v;
      }
    }
  }
}

// ---------------------------------------------------------------------------
// fp32 batched GEMM (attention + k2). outBf: bf16 store.
// ---------------------------------------------------------------------------
__global__ __launch_bounds__(256) void mk_gemm(
    const float* __restrict__ A, const float* __restrict__ B,
    const float* __restrict__ bias, void* __restrict__ C,
    int M, int N, int K, int lda, int ldb, int ldc,
    int zdiv,
    long sA1, long sA2, long sB1, long sB2, long sC1, long sC2,
    int bIsNT, int tilesN, int outBf)
{
  int z = blockIdx.y;
  int z1 = z / zdiv, z2 = z - z1 * zdiv;
  const float* Ab = A + (long)z1 * sA1 + (long)z2 * sA2;
  const float* Bb = B + (long)z1 * sB1 + (long)z2 * sB2;
  long coff = (long)z1 * sC1 + (long)z2 * sC2;

  int tile = blockIdx.x;
  int tm = tile / tilesN, tn = tile - tm * tilesN;
  int m0 = tm << 6, n0 = tn << 6;

  __shared__ float As[16][68];
  __shared__ float Bs[16][68];

  int tid = threadIdx.x;
  int tx = tid & 15, ty = tid >> 4;
  int lrow = tid >> 2;
  int lk = (tid & 3) << 2;
  int bkk = tid >> 4;
  int bnn = (tid & 15) << 2;

  float acc[4][4];
#pragma unroll
  for (int i = 0; i < 4; i++)
#pragma unroll
    for (int j = 0; j < 4; j++) acc[i][j] = 0.f;

  for (int k0 = 0; k0 < K; k0 += 16) {
    {
      int gm = m0 + lrow;
      float4 v = {0.f, 0.f, 0.f, 0.f};
      if (gm < M) v = *(const float4*)(Ab + (long)gm * lda + (k0 + lk));
      As[lk + 0][lrow] = v.x; As[lk + 1][lrow] = v.y;
      As[lk + 2][lrow] = v.z; As[lk + 3][lrow] = v.w;
    }
    if (bIsNT) {
      int gn = n0 + lrow;
      float4 v = {0.f, 0.f, 0.f, 0.f};
      if (gn < N) v = *(const float4*)(Bb + (long)gn * ldb + (k0 + lk));
      Bs[lk + 0][lrow] = v.x; Bs[lk + 1][lrow] = v.y;
      Bs[lk + 2][lrow] = v.z; Bs[lk + 3][lrow] = v.w;
    } else {
      int gn = n0 + bnn;
      float4 v = {0.f, 0.f, 0.f, 0.f};
      if (gn + 3 < N) {
        v = *(const float4*)(Bb + (long)(k0 + bkk) * ldb + gn);
      } else {
        float t0 = (gn + 0 < N) ? Bb[(long)(k0 + bkk) * ldb + gn + 0] : 0.f;
        float t1 = (gn + 1 < N) ? Bb[(long)(k0 + bkk) * ldb + gn + 1] : 0.f;
        float t2 = (gn + 2 < N) ? Bb[(long)(k0 + bkk) * ldb + gn + 2] : 0.f;
        float t3 = (gn + 3 < N) ? Bb[(long)(k0 + bkk) * ldb + gn + 3] : 0.f;
        v.x = t0; v.y = t1; v.z = t2; v.w = t3;
      }
      *(float4*)&Bs[bkk][bnn] = v;
    }
    __syncthreads();
#pragma unroll
    for (int kk = 0; kk < 16; kk++) {
      float4 a = *(const float4*)&As[kk][ty << 2];
      float4 b = *(const float4*)&Bs[kk][tx << 2];
      acc[0][0] += a.x * b.x; acc[0][1] += a.x * b.y; acc[0][2] += a.x * b.z; acc[0][3] += a.x * b.w;
      acc[1][0] += a.y * b.x; acc[1][1] += a.y * b.y; acc[1][2] += a.y * b.z; acc[1][3] += a.y * b.w;
      acc[2][0] += a.z * b.x; acc[2][1] += a.z * b.y; acc[2][2] += a.z * b.z; acc[2][3] += a.z * b.w;
      acc[3][0] += a.w * b.x; acc[3][1] += a.w * b.y; acc[3][2] += a.w * b.z; acc[3][3] += a.w * b.w;
    }
    __syncthreads();
  }

#pragma unroll
  for (int i = 0; i < 4; i++) {
    int gm = m0 + (ty << 2) + i;
    if (gm >= M) continue;
#pragma unroll
    for (int j = 0; j < 4; j++) {
      int gn = n0 + (tx << 2) + j;
      if (gn >= N) continue;
      float v = acc[i][j];
      if (bias) v += bias[gn];
      long idx = coff + (long)gm * ldc + gn;
      if (outBf) ((ushortt*)C)[idx] = f2b(v);
      else ((float*)C)[idx] = v;
    }
  }
}

// ---------------------------------------------------------------------------
__global__ __launch_bounds__(256) void mk_softmax(float* __restrict__ scores, float scale)
{
  int row = (blockIdx.x << 2) + (threadIdx.x >> 6);
  int lane = threadIdx.x & 63;
  float* p = scores + (long)row * 256 + (lane << 2);
  float4 v = *(const float4*)p;
  float m = fmaxf(fmaxf(v.x, v.y), fmaxf(v.z, v.w));
#pragma unroll
  for (int o = 32; o; o >>= 1) m = fmaxf(m, __shfl_xor(m, o, 64));
  v.x = expf(scale * (v.x - m));
  v.y = expf(scale * (v.y - m));
  v.z = expf(scale * (v.z - m));
  v.w = expf(scale * (v.w - m));
  float s = v.x + v.y + v.z + v.w;
#pragma unroll
  for (int o = 32; o; o >>= 1) s += __shfl_xor(s, o, 64);
  float r = 1.f / s;
  v.x *= r; v.y *= r; v.z *= r; v.w *= r;
  *(float4*)p = v;
}

// ---------------------------------------------------------------------------
__global__ __launch_bounds__(256) void mk_gates(const float* __restrict__ q2,
                                                const float* __restrict__ k2,
                                                float* __restrict__ gacc)
{
  __shared__ float k2p[8 * 808];
  int b = blockIdx.x >> 4, q = blockIdx.x & 15;
  for (int i = threadIdx.x; i < 6144; i += 256) {
    int e = i / 768, rem = i - e * 768;
    int h = rem / 96, j = rem - h * 96;
    k2p[e * 808 + h * 100 + j] = k2[i];
  }
  __syncthreads();
  const float scale = 0.10206207261596577f;
  int wid = threadIdx.x >> 6, lane = threadIdx.x & 63;
  int h = lane >> 3, e = lane & 7;
  const float* kp = &k2p[e * 808 + h * 100];
  float accL = 0.f;
#pragma unroll
  for (int ti = 0; ti < 4; ti++) {
    int l = q * 16 + wid * 4 + ti;
    const float* qh = q2 + ((long)b * LTOK + l) * DIMC + h * 96;
    float sum = 0.f;
#pragma unroll
    for (int j = 0; j < 96; j += 4) {
      float4 qv = *(const float4*)(qh + j);
      float4 kv = *(const float4*)(kp + j);
      sum += qv.x * kv.x + qv.y * kv.y + qv.z * kv.z + qv.w * kv.w;
    }
    float s = sum * scale;
    float mx = s;
#pragma unroll
    for (int o = 1; o <= 4; o <<= 1) mx = fmaxf(mx, __shfl_xor(mx, o, 64));
    float ex = expf(s - mx);
    float se = ex;
#pragma unroll
    for (int o = 1; o <= 4; o <<= 1) se += __shfl_xor(se, o, 64);
    accL += ex / se;
  }
#pragma unroll
  for (int o = 8; o <= 32; o <<= 1) accL += __shfl_xor(accL, o, 64);
  __shared__ float red[4][8];
  if (lane < 8) red[wid][lane] = accL;
  __syncthreads();
  if (threadIdx.x < 8) {
    float v = red[0][threadIdx.x] + red[1][threadIdx.x] +
              red[2][threadIdx.x] + red[3][threadIdx.x];
    atomicAdd(&gacc[b * 8 + threadIdx.x], v);
  }
}

__global__ __launch_bounds__(64) void mk_gatetop(const float* __restrict__ gacc,
                                                 int* __restrict__ pe,
                                                 float* __restrict__ pw)
{
  int b = threadIdx.x;
  if (b >= 16) return;
  float g[8];
  for (int e = 0; e < 8; e++) g[e] = gacc[b * 8 + e] * (1.f / (8.f * 256.f));
  float mx = g[0];
  for (int e = 1; e < 8; e++) mx = fmaxf(mx, g[e]);
  float se = 0.f;
  for (int e = 0; e < 8; e++) { g[e] = expf(g[e] - mx); se += g[e]; }
  for (int e = 0; e < 8; e++) g[e] /= se;
  int i0 = 0;
  for (int e = 1; e < 8; e++) if (g[e] > g[i0]) i0 = e;
  int i1 = (i0 == 0) ? 1 : 0;
  for (int e = 0; e < 8; e++) if (e != i0 && g[e] > g[i1]) i1 = e;
  float w0 = 1.f / (1.f + expf(g[i1] - g[i0]));
  pe[2 * b] = i0; pe[2 * b + 1] = i1;
  pw[2 * b] = w0; pw[2 * b + 1] = 1.f - w0;
}

// ---------------------------------------------------------------------------
// Depthwise 3x3 conv + bias + SiLU, reading split xz_x (stride 768).
// ---------------------------------------------------------------------------
__global__ __launch_bounds__(768) void mk_conv(const float* __restrict__ xzx,
                                               const float* __restrict__ cw,
                                               const float* __restrict__ cb,
                                               const int* __restrict__ pe,
                                               float* __restrict__ xc)
{
  int blk = blockIdx.x;
  int p = blk >> 8, t = blk & 255;
  int e = pe[p];
  int h = t >> 4, w = t & 15;
  int c = threadIdx.x;
  const float* wp = cw + ((long)e * DIMC + c) * 9;
  float acc = cb[e * DIMC + c];
#pragma unroll
  for (int dh = 0; dh < 3; dh++) {
    int hh = h + dh - 1;
    if (hh < 0 || hh > 15) continue;
#pragma unroll
    for (int dw = 0; dw < 3; dw++) {
      int ww = w + dw - 1;
      if (ww < 0 || ww > 15) continue;
      acc += xzx[((long)p * LTOK + hh * 16 + ww) * DIMC + c] * wp[dh * 3 + dw];
    }
  }
  xc[((long)p * LTOK + t) * DIMC + c] = acc / (1.f + expf(-acc));
}

__device__ __forceinline__ int tmap(int dir, int s) {
  if (dir == 0) return s;
  if (dir == 1) return 255 - s;
  if (dir == 2) return ((s & 15) << 4) | (s >> 4);
  int u = 255 - s;
  return ((u & 15) << 4) | (u >> 4);
}

// ---------------------------------------------------------------------------
__global__ __launch_bounds__(256) void mk_dbl(const float* __restrict__ xc,
                                              const float* __restrict__ xproj,
                                              const int* __restrict__ pe,
                                              float* __restrict__ dblm)
{
  int p = blockIdx.x >> 2, q = blockIdx.x & 3;
  int e = pe[p];
  int tl = threadIdx.x & 63;
  int dir = threadIdx.x >> 6;
  int m = q * 64 + tl;
  const float* xr = xc + ((long)p * LTOK + m) * DIMC;
  const float* wbase = xproj + (long)(e * 4 + dir) * 6 * DIMC;
  float s[6] = {0.f, 0.f, 0.f, 0.f, 0.f, 0.f};
  for (int c = 0; c < DIMC; c += 4) {
    float4 xv = *(const float4*)(xr + c);
#pragma unroll
    for (int j = 0; j < 6; j++) {
      float4 wv = *(const float4*)(wbase + j * DIMC + c);
      s[j] += xv.x * wv.x + xv.y * wv.y + xv.z * wv.z + xv.w * wv.w;
    }
  }
  float* o = dblm + ((long)p * LTOK + m) * 24 + dir * 6;
#pragma unroll
  for (int j = 0; j < 6; j++) o[j] = s[j];
}

// ---------------------------------------------------------------------------
// Scan pass A: thread = (p,dir,seg,d); 32-step segment from h=0.
// Stores (prod of decays, local h) per segment. 3072 blocks x 256 thr.
// ---------------------------------------------------------------------------
__global__ __launch_bounds__(256) void mk_scanA(const float* __restrict__ xc,
                                                const float* __restrict__ dblm,
                                                const float* __restrict__ dtw,
                                                const float* __restrict__ dtb,
                                                const float* __restrict__ Alog,
                                                const int* __restrict__ pe,
                                                float* __restrict__ segA,
                                                float* __restrict__ segH)
{
  int g = blockIdx.x * 256 + threadIdx.x;   // 786432
  int d = g % 768;
  int r = g / 768;
  int seg = r & 7;
  int dir = (r >> 3) & 3;
  int p = r >> 5;
  int e = pe[p];
  const float* xcp = xc + (long)p * LTOK * DIMC;
  const float* dbp = dblm + (long)p * LTOK * 24 + dir * 6;
  long pb = (long)(e * 4 + dir) * DIMC + d;
  float4 wv = *(const float4*)(dtw + pb * 4);
  float bdt = dtb[pb];
  float Ad = -expf(Alog[pb]);
  float h = 0.f, ap = 1.f;
  int t0 = seg << 5;
  for (int tb = 0; tb < 32; tb += 8) {
    float dec[8], u[8];
#pragma unroll
    for (int i = 0; i < 8; i++) {
      int t = t0 + tb + i;
      int m = tmap(dir, t);
      const float* db = dbp + (long)m * 24;
      float2 d01 = *(const float2*)(db);
      float2 d23 = *(const float2*)(db + 2);
      float bq = db[4];
      float xr = wv.x * d01.x + wv.y * d01.y + wv.z * d23.x + wv.w * d23.y + bdt;
      float dt = fmaxf(xr, 0.f) + log1pf(expf(-fabsf(xr)));
      float xv = xcp[(long)m * DIMC + d];
      dec[i] = expf(dt * Ad);
      u[i] = dt * xv * bq;
    }
#pragma unroll
    for (int i = 0; i < 8; i++) {
      h = dec[i] * h + u[i];
      ap *= dec[i];
    }
  }
  segA[g] = ap;
  segH[g] = h;
}

// ---------------------------------------------------------------------------
// Scan pass B: block = (p, 16-channel group); 512 thr = 4 dirs x 8 segs x 16 ch.
// h_init from segment combine; replay 32 steps; LDS atomic direction-merge;
// coalesced epilogue write with D-term folded. 1536 blocks.
// ---------------------------------------------------------------------------
__global__ __launch_bounds__(512) void mk_scanB(const float* __restrict__ xc,
                                                const float* __restrict__ dblm,
                                                const float* __restrict__ dtw,
                                                const float* __restrict__ dtb,
                                                const float* __restrict__ Alog,
                                                const float* __restrict__ Dp,
                                                const int* __restrict__ pe,
                                                const float* __restrict__ segA,
                                                const float* __restrict__ segH,
                                                float* __restrict__ yac)
{
  __shared__ float yS[256 * 17];   // 17.4 KB
  __shared__ float dsum[16];
  int blk = blockIdx.x;
  int p = blk / 48, cg = blk - p * 48;
  int c0 = cg << 4;
  int e = pe[p];
  int tid = threadIdx.x;
  for (int i = tid; i < 256 * 17; i += 512) yS[i] = 0.f;
  if (tid < 16) {
    float s = 0.f;
#pragma unroll
    for (int dd = 0; dd < 4; dd++) s += Dp[(long)(e * 4 + dd) * DIMC + c0 + tid];
    dsum[tid] = s;
  }
  __syncthreads();

  int c = tid & 15;
  int rr = tid >> 4;
  int seg = rr & 7;
  int dir = rr >> 3;
  int d = c0 + c;
  const float* xcp = xc + (long)p * LTOK * DIMC;
  const float* dbp = dblm + (long)p * LTOK * 24 + dir * 6;
  long base = ((long)(p * 32 + dir * 8)) * 768 + d;
  float hinit = 0.f;
  for (int j = 0; j < seg; j++) {
    long ix = base + (long)j * 768;
    hinit = segA[ix] * hinit + segH[ix];
  }
  long pb = (long)(e * 4 + dir) * DIMC + d;
  float4 wv = *(const float4*)(dtw + pb * 4);
  float bdt = dtb[pb];
  float Ad = -expf(Alog[pb]);
  float h = hinit;
  int t0 = seg << 5;
  for (int tb = 0; tb < 32; tb += 8) {
    float dec[8], u[8], cc[8];
    int mm[8];
#pragma unroll
    for (int i = 0; i < 8; i++) {
      int t = t0 + tb + i;
      int m = tmap(dir, t);
      mm[i] = m;
      const float* db = dbp + (long)m * 24;
      float2 d01 = *(const float2*)(db);
      float2 d23 = *(const float2*)(db + 2);
      float2 d45 = *(const float2*)(db + 4);
      float xr = wv.x * d01.x + wv.y * d01.y + wv.z * d23.x + wv.w * d23.y + bdt;
      float dt = fmaxf(xr, 0.f) + log1pf(expf(-fabsf(xr)));
      float xv = xcp[(long)m * DIMC + d];
      dec[i] = expf(dt * Ad);
      u[i] = dt * xv * d45.x;
      cc[i] = d45.y;
    }
#pragma unroll
    for (int i = 0; i < 8; i++) {
      h = dec[i] * h + u[i];
      atomicAdd(&yS[mm[i] * 17 + c], h * cc[i]);
    }
  }
  __syncthreads();

  float* yp = yac + (long)p * LTOK * DIMC + c0;
  for (int i = tid; i < 256 * 16; i += 512) {
    int t = i >> 4, cz = i & 15;
    yp[(long)t * DIMC + cz] = yS[t * 17 + cz] + xcp[(long)t * DIMC + c0 + cz] * dsum[cz];
  }
}

// ---------------------------------------------------------------------------
__global__ __launch_bounds__(768) void mk_lnfin(const float* __restrict__ yac,
                                                const float* __restrict__ xzz,
                                                const float* __restrict__ lns,
                                                const float* __restrict__ lnb,
                                                const int* __restrict__ pe,
                                                float* __restrict__ eo)
{
  int p = blockIdx.x;
  int e = pe[p];
  int tid = threadIdx.x;
  int wid = tid >> 6, lane = tid & 63;
  float ls[12], lb[12], acc[12];
#pragma unroll
  for (int i = 0; i < 12; i++) {
    int d = i * 64 + lane;
    ls[i] = lns[e * DIMC + d];
    lb[i] = lnb[e * DIMC + d];
    acc[i] = 0.f;
  }
  for (int t = wid; t < 256; t += 12) {
    const float* yr = yac + ((long)p * LTOK + t) * DIMC;
    const float* zr = xzz + ((long)p * LTOK + t) * DIMC;
    float v[12];
    float s = 0.f;
#pragma unroll
    for (int i = 0; i < 12; i++) { v[i] = yr[i * 64 + lane]; s += v[i]; }
#pragma unroll
    for (int o = 32; o; o >>= 1) s += __shfl_xor(s, o, 64);
    float mu = s * (1.f / 768.f);
    float sq = 0.f;
#pragma unroll
    for (int i = 0; i < 12; i++) { float dlt = v[i] - mu; sq += dlt * dlt; }
#pragma unroll
    for (int o = 32; o; o >>= 1) sq += __shfl_xor(sq, o, 64);
    float rs = rsqrtf(sq * (1.f / 768.f) + 1e-5f);
#pragma unroll
    for (int i = 0; i < 12; i++) {
      float y = (v[i] - mu) * rs * ls[i] + lb[i];
      float z = zr[i * 64 + lane];
      y *= z / (1.f + expf(-z));
      acc[i] += y;
    }
  }
  __shared__ float sacc[768];
  sacc[tid] = 0.f;
  __syncthreads();
#pragma unroll
  for (int i = 0; i < 12; i++) atomicAdd(&sacc[i * 64 + lane], acc[i]);
  __syncthreads();
  eo[(long)p * DIMC + tid] = sacc[tid] * (1.f / 256.f);
}

__global__ __launch_bounds__(768) void mk_out(const float* __restrict__ eo,
                                              const float* __restrict__ pw,
                                              float* __restrict__ out)
{
  int b = blockIdx.x, d = threadIdx.x;
  float v = pw[2 * b] * eo[(long)(2 * b) * DIMC + d] +
            pw[2 * b + 1] * eo[(long)(2 * b + 1) * DIMC + d];
  out[b * DIMC + d] = v;
}

// ---------------------------------------------------------------------------
extern "C" void kernel_launch(void* const* d_in, const int* in_sizes, int n_in,
                              void* d_out, int out_size, void* d_ws, size_t ws_size,
                              hipStream_t stream)
{
  const float* x        = (const float*)d_in[0];
  const float* sa_in_w  = (const float*)d_in[1];
  const float* sa_in_b  = (const float*)d_in[2];
  const float* sa_out_w = (const float*)d_in[3];
  const float* sa_out_b = (const float*)d_in[4];
  const float* ca_in_w  = (const float*)d_in[5];
  const float* ca_in_b  = (const float*)d_in[6];
  const float* eq       = (const float*)d_in[7];
  const float* e_in_w   = (const float*)d_in[8];
  const float* e_in_b   = (const float*)d_in[9];
  const float* e_conv_w = (const float*)d_in[10];
  const float* e_conv_b = (const float*)d_in[11];
  const float* e_xproj  = (const float*)d_in[12];
  const float* e_dtw    = (const float*)d_in[13];
  const float* e_dtb    = (const float*)d_in[14];
  const float* e_Alog   = (const float*)d_in[15];
  const float* e_D      = (const float*)d_in[16];
  const float* e_lns    = (const float*)d_in[17];
  const float* e_lnb    = (const float*)d_in[18];
  float* out = (float*)d_out;

  float* ws = (float*)d_ws;
  // ---- attention phase ----
  float*   qkv    = ws + 0;                      // 0 .. 9,437,184
  float*   scores = ws + 9437184;                // .. 17,825,792
  ushortt* ctxa_b = (ushortt*)(ws + 17825792);   // 3.1M bf16 (1.57M slots) .. 19,398,656
  ushortt* xb     = (ushortt*)(ws + 20971520);   // .. 22,544,384
  ushortt* wqkv_b = (ushortt*)(ws + 22544384);   // 884,736 slots .. 23,429,120
  ushortt* saow_b = (ushortt*)(ws + 23429120);   // 294,912 slots .. 23,724,032
  ushortt* caw_b  = (ushortt*)(ws + 23724032);   // 294,912 slots .. 24,018,944
  ushortt* ctx_b  = (ushortt*)(ws + 3145728);    // .. 4,718,592 (in dead qkv)
  float*   q2     = ws + 4718592;                // .. 7,864,320 (in dead qkv)
  // ---- persistent smalls ----
  float*   k2     = ws + 25165824;
  int*     pe     = (int*)(ws + 25171968);
  float*   pw     = ws + 25172000;
  float*   eo     = ws + 25172032;               // .. 25,196,608
  float*   dblm   = ws + 25196608;               // .. 25,393,216
  float*   gacc   = ws + 25393216;               // .. 25,393,344 (peak 101.6MB)
  // ---- expert phase (attention regions dead) ----
  float*   xz_x   = ws + 0;                      // .. 6,291,456
  float*   xz_z   = ws + 6291456;                // .. 12,582,912 (live->lnfin)
  ushortt* ew_b   = (ushortt*)(ws + 12582912);   // .. 17,301,504 (dead scores)
  float*   xc     = ws + 12582912;               // .. 18,874,368 (after ew_b dead)
  float*   yac    = ws + 18874368;               // .. 25,165,824
  float*   segA   = ws + 0;                      // .. 786,432 (xz_x dead post-conv)
  float*   segH   = ws + 786432;                 // .. 1,572,864

  const float scale = 0.10206207261596577f;

  // 0. fused upfront casts: x, sa_in_w, sa_out_w, ca_in_w[:768]
  mk_mcast4<<<5952, 256, 0, stream>>>(x, xb, sa_in_w, wqkv_b, sa_out_w, saow_b,
                                      ca_in_w, caw_b);
  // 1. qkv = x @ sa_in_w^T + b  (4096x2304x768 MFMA, fp32 out)
  mk_mfma<<<dim3(32 * 18, 1), 256, 0, stream>>>(xb, wqkv_b, sa_in_b, qkv,
      768, 768, 768, 2304, 0, 0, 0, 0, nullptr, 18, 0, 1 << 30, nullptr, 0);
  // 2. scores = q @ k^T  (256x256x96, Z=128)
  mk_gemm<<<dim3(16, 128), 256, 0, stream>>>(qkv, qkv + 768, nullptr, scores,
      256, 256, 96, 2304, 2304, 256, 8, 589824, 96, 589824, 96, 524288, 65536, 1, 4, 0);
  // 3. softmax
  mk_softmax<<<8192, 256, 0, stream>>>(scores, scale);
  // 4. ctxa = att @ v  -> bf16 directly
  mk_gemm<<<dim3(8, 128), 256, 0, stream>>>(scores, qkv + 1536, nullptr, ctxa_b,
      256, 96, 256, 256, 2304, 768, 8, 524288, 65536, 589824, 96, 196608, 96, 0, 2, 1);
  // 4b. cast expert weights into dead scores region
  mk_cast<<<9216, 256, 0, stream>>>(e_in_w, ew_b, 9437184);
  // 5. ctx = ctxa @ sa_out_w^T + b -> bf16 directly (4096x768x768 MFMA)
  mk_mfma<<<dim3(32 * 6, 1), 256, 0, stream>>>(ctxa_b, saow_b, sa_out_b, ctx_b,
      768, 768, 768, 768, 0, 0, 0, 0, nullptr, 6, 1, 1 << 30, nullptr, 0);
  // 6. q2 = ctx @ ca_in_w[:768]^T + b (fp32 out)
  mk_mfma<<<dim3(32 * 6, 1), 256, 0, stream>>>(ctx_b, caw_b, ca_in_b, q2,
      768, 768, 768, 768, 0, 0, 0, 0, nullptr, 6, 0, 1 << 30, nullptr, 0);
  // 7. k2 = eq @ ca_in_w[768:]^T + b  (8x768x768 fp32)
  mk_gemm<<<dim3(12, 1), 256, 0, stream>>>(eq, ca_in_w + 589824, ca_in_b + 768, k2,
      8, 768, 768, 768, 768, 768, 1, 0, 0, 0, 0, 0, 0, 1, 12, 0);
  // 8. gate
  hipMemsetAsync(gacc, 0, 128 * sizeof(float), stream);
  mk_gates<<<256, 256, 0, stream>>>(q2, k2, gacc);
  mk_gatetop<<<1, 64, 0, stream>>>(gacc, pe, pw);
  // 9. xz = x @ e_in_w[e]^T + b (256x1536x768, Z=32) split -> xz_x | xz_z
  mk_mfma<<<dim3(2 * 12, 32), 256, 0, stream>>>(xb, ew_b, e_in_b, xz_x,
      768, 768, 768, 768, 196608, 1179648, 196608, 1536, pe, 12, 0, 768, xz_z, 768);
  // 10. depthwise conv + SiLU
  mk_conv<<<32 * 256, 768, 0, stream>>>(xz_x, e_conv_w, e_conv_b, pe, xc);
  // 11. dblm projections
  mk_dbl<<<128, 256, 0, stream>>>(xc, e_xproj, pe, dblm);
  // 12. two-pass segmented scan (xz_x region dead -> segA/segH)
  mk_scanA<<<3072, 256, 0, stream>>>(xc, dblm, e_dtw, e_dtb, e_Alog, pe, segA, segH);
  mk_scanB<<<1536, 512, 0, stream>>>(xc, dblm, e_dtw, e_dtb, e_Alog, e_D, pe,
                                     segA, segH, yac);
  // 13. LN + silu(z) + token mean
  mk_lnfin<<<32, 768, 0, stream>>>(yac, xz_z, e_lns, e_lnb, pe, eo);
  // 14. weighted top-2 combine
  mk_out<<<16, 768, 0, stream>>>(eo, pw, out);

  (void)in_sizes; (void)n_in; (void)out_size; (void)ws_size;
}

// Round 9
// 782.388 us; speedup vs baseline: 1.0958x; 1.0958x over previous
//
#include <hip/hip_runtime.h>
#include <hip/hip_bf16.h>

// MoEFSCIL: B=16, H=W=16, L=256, DIM=768, NH=8, HD=96, NEXP=8, TOPK=2.
// fp32 in/out. Big GEMMs bf16 MFMA; attention fp32.
// Scan: single fused kernel — segment scan with register-cached (dec,u),
// in-block segment combine, LDS direction merge, HW exp2/log2 via
// __builtin_amdgcn_* (plain __exp2f/__log2f clash with glibc math.h).

#define LTOK 256
#define DIMC 768

typedef unsigned short ushortt;
typedef __attribute__((ext_vector_type(8))) short bf16x8;
typedef __attribute__((ext_vector_type(4))) float f32x4;

#define LOG2E 1.44269504f
#define LN2   0.69314718f

__device__ __forceinline__ float fexp2(float x) { return __builtin_amdgcn_exp2f(x); }
__device__ __forceinline__ float flog2(float x) { return __builtin_amdgcn_logf(x); }

__device__ __forceinline__ ushortt f2b(float f) {
  union { float f; unsigned u; } c; c.f = f;
  unsigned r = (c.u + 0x7FFFu + ((c.u >> 16) & 1u)) >> 16;
  return (ushortt)r;
}

// ---------------------------------------------------------------------------
// Fused 4-tensor fp32->bf16 cast (x, sa_in_w, sa_out_w, ca_in_w[:768] rows).
// ---------------------------------------------------------------------------
__global__ __launch_bounds__(256) void mk_mcast4(
    const float* __restrict__ s0, ushortt* __restrict__ d0,
    const float* __restrict__ s1, ushortt* __restrict__ d1,
    const float* __restrict__ s2, ushortt* __restrict__ d2,
    const float* __restrict__ s3, ushortt* __restrict__ d3)
{
  long g = (long)blockIdx.x * 256 + threadIdx.x;   // float4 chunk id
  const float* s; ushortt* dst; long o;
  if (g < 786432)       { s = s0; dst = d0; o = g; }
  else if (g < 1228800) { s = s1; dst = d1; o = g - 786432; }
  else if (g < 1376256) { s = s2; dst = d2; o = g - 1228800; }
  else                  { s = s3; dst = d3; o = g - 1376256; }
  o <<= 2;
  float4 v = *(const float4*)(s + o);
  ushort4 w;
  w.x = f2b(v.x); w.y = f2b(v.y); w.z = f2b(v.z); w.w = f2b(v.w);
  *(ushort4*)(dst + o) = w;
}

__global__ __launch_bounds__(256) void mk_cast(const float* __restrict__ in,
                                               ushortt* __restrict__ outp, long n)
{
  long i = ((long)blockIdx.x * 256 + threadIdx.x) * 4;
  if (i + 3 < n) {
    float4 v = *(const float4*)(in + i);
    ushort4 o;
    o.x = f2b(v.x); o.y = f2b(v.y); o.z = f2b(v.z); o.w = f2b(v.w);
    *(ushort4*)(outp + i) = o;
  }
}

// ---------------------------------------------------------------------------
// bf16 MFMA GEMM: C[z] = A[z](M,K) @ B[z](N,K)^T + bias.
// ---------------------------------------------------------------------------
__global__ __launch_bounds__(256) void mk_mfma(
    const ushortt* __restrict__ A, const ushortt* __restrict__ B,
    const float* __restrict__ bias, void* __restrict__ C,
    int K, int lda, int ldb, int ldc,
    long sA, long sB, long sC, long sBias,
    const int* __restrict__ pairExp, int tilesN,
    int outBf, int splitN, void* __restrict__ C2, int ldc2)
{
  int z = blockIdx.y;
  long aoff = 0, boff = 0, coff = 0, biasoff = 0;
  if (pairExp) {
    int e = pairExp[z];
    aoff = (long)(z >> 1) * sA; boff = (long)e * sB;
    coff = (long)z * sC; biasoff = (long)e * sBias;
  }
  int tile = blockIdx.x;
  int tm = tile / tilesN, tn = tile - tm * tilesN;
  long m0 = (long)tm << 7, n0 = (long)tn << 7;

  __shared__ ushortt As[128][40];
  __shared__ ushortt Bs[128][40];

  int tid = threadIdx.x;
  int lane = tid & 63, wvi = tid >> 6;
  int wr = wvi >> 1, wc = wvi & 1;
  int lm = lane & 15, lg = lane >> 4;

  f32x4 zero4 = {0.f, 0.f, 0.f, 0.f};
  f32x4 acc[4][4];
#pragma unroll
  for (int i = 0; i < 4; i++)
#pragma unroll
    for (int j = 0; j < 4; j++) acc[i][j] = zero4;

  const ushortt* Ab = A + aoff;
  const ushortt* Bb = B + boff;

  for (int k0 = 0; k0 < K; k0 += 32) {
#pragma unroll
    for (int h = 0; h < 2; h++) {
      int q = tid + h * 256;
      int row = q >> 2, ck = (q & 3) << 3;
      *(uint4*)&As[row][ck] = *(const uint4*)(Ab + (m0 + row) * lda + k0 + ck);
      *(uint4*)&Bs[row][ck] = *(const uint4*)(Bb + (n0 + row) * ldb + k0 + ck);
    }
    __syncthreads();
    bf16x8 af[4], bfr[4];
#pragma unroll
    for (int i = 0; i < 4; i++)
      af[i] = *(const bf16x8*)&As[wr * 64 + i * 16 + lm][lg << 3];
#pragma unroll
    for (int j = 0; j < 4; j++)
      bfr[j] = *(const bf16x8*)&Bs[wc * 64 + j * 16 + lm][lg << 3];
#pragma unroll
    for (int i = 0; i < 4; i++)
#pragma unroll
      for (int j = 0; j < 4; j++)
        acc[i][j] = __builtin_amdgcn_mfma_f32_16x16x32_bf16(af[i], bfr[j], acc[i][j], 0, 0, 0);
    __syncthreads();
  }

#pragma unroll
  for (int mt = 0; mt < 4; mt++) {
#pragma unroll
    for (int nt = 0; nt < 4; nt++) {
      long grow = m0 + wr * 64 + mt * 16 + lg * 4;
      long gcol = n0 + wc * 64 + nt * 16 + lm;
      float bv = bias ? bias[biasoff + gcol] : 0.f;
      void* Ct; long col; int ld;
      if ((int)gcol < splitN) { Ct = C; col = gcol; ld = ldc; }
      else { Ct = C2; col = gcol - splitN; ld = ldc2; }
#pragma unroll
      for (int r = 0; r < 4; r++) {
        float v = acc[mt][nt][r] + bv;
        long idx = coff + (grow + r) * ld + col;
        if (outBf) ((ushortt*)Ct)[idx] = f2b(v);
        else ((float*)Ct)[idx] = v;
      }
    }
  }
}

// ---------------------------------------------------------------------------
// fp32 batched GEMM (attention + k2). outBf: bf16 store.
// ---------------------------------------------------------------------------
__global__ __launch_bounds__(256) void mk_gemm(
    const float* __restrict__ A, const float* __restrict__ B,
    const float* __restrict__ bias, void* __restrict__ C,
    int M, int N, int K, int lda, int ldb, int ldc,
    int zdiv,
    long sA1, long sA2, long sB1, long sB2, long sC1, long sC2,
    int bIsNT, int tilesN, int outBf)
{
  int z = blockIdx.y;
  int z1 = z / zdiv, z2 = z - z1 * zdiv;
  const float* Ab = A + (long)z1 * sA1 + (long)z2 * sA2;
  const float* Bb = B + (long)z1 * sB1 + (long)z2 * sB2;
  long coff = (long)z1 * sC1 + (long)z2 * sC2;

  int tile = blockIdx.x;
  int tm = tile / tilesN, tn = tile - tm * tilesN;
  int m0 = tm << 6, n0 = tn << 6;

  __shared__ float As[16][68];
  __shared__ float Bs[16][68];

  int tid = threadIdx.x;
  int tx = tid & 15, ty = tid >> 4;
  int lrow = tid >> 2;
  int lk = (tid & 3) << 2;
  int bkk = tid >> 4;
  int bnn = (tid & 15) << 2;

  float acc[4][4];
#pragma unroll
  for (int i = 0; i < 4; i++)
#pragma unroll
    for (int j = 0; j < 4; j++) acc[i][j] = 0.f;

  for (int k0 = 0; k0 < K; k0 += 16) {
    {
      int gm = m0 + lrow;
      float4 v = {0.f, 0.f, 0.f, 0.f};
      if (gm < M) v = *(const float4*)(Ab + (long)gm * lda + (k0 + lk));
      As[lk + 0][lrow] = v.x; As[lk + 1][lrow] = v.y;
      As[lk + 2][lrow] = v.z; As[lk + 3][lrow] = v.w;
    }
    if (bIsNT) {
      int gn = n0 + lrow;
      float4 v = {0.f, 0.f, 0.f, 0.f};
      if (gn < N) v = *(const float4*)(Bb + (long)gn * ldb + (k0 + lk));
      Bs[lk + 0][lrow] = v.x; Bs[lk + 1][lrow] = v.y;
      Bs[lk + 2][lrow] = v.z; Bs[lk + 3][lrow] = v.w;
    } else {
      int gn = n0 + bnn;
      float4 v = {0.f, 0.f, 0.f, 0.f};
      if (gn + 3 < N) {
        v = *(const float4*)(Bb + (long)(k0 + bkk) * ldb + gn);
      } else {
        float t0 = (gn + 0 < N) ? Bb[(long)(k0 + bkk) * ldb + gn + 0] : 0.f;
        float t1 = (gn + 1 < N) ? Bb[(long)(k0 + bkk) * ldb + gn + 1] : 0.f;
        float t2 = (gn + 2 < N) ? Bb[(long)(k0 + bkk) * ldb + gn + 2] : 0.f;
        float t3 = (gn + 3 < N) ? Bb[(long)(k0 + bkk) * ldb + gn + 3] : 0.f;
        v.x = t0; v.y = t1; v.z = t2; v.w = t3;
      }
      *(float4*)&Bs[bkk][bnn] = v;
    }
    __syncthreads();
#pragma unroll
    for (int kk = 0; kk < 16; kk++) {
      float4 a = *(const float4*)&As[kk][ty << 2];
      float4 b = *(const float4*)&Bs[kk][tx << 2];
      acc[0][0] += a.x * b.x; acc[0][1] += a.x * b.y; acc[0][2] += a.x * b.z; acc[0][3] += a.x * b.w;
      acc[1][0] += a.y * b.x; acc[1][1] += a.y * b.y; acc[1][2] += a.y * b.z; acc[1][3] += a.y * b.w;
      acc[2][0] += a.z * b.x; acc[2][1] += a.z * b.y; acc[2][2] += a.z * b.z; acc[2][3] += a.z * b.w;
      acc[3][0] += a.w * b.x; acc[3][1] += a.w * b.y; acc[3][2] += a.w * b.z; acc[3][3] += a.w * b.w;
    }
    __syncthreads();
  }

#pragma unroll
  for (int i = 0; i < 4; i++) {
    int gm = m0 + (ty << 2) + i;
    if (gm >= M) continue;
#pragma unroll
    for (int j = 0; j < 4; j++) {
      int gn = n0 + (tx << 2) + j;
      if (gn >= N) continue;
      float v = acc[i][j];
      if (bias) v += bias[gn];
      long idx = coff + (long)gm * ldc + gn;
      if (outBf) ((ushortt*)C)[idx] = f2b(v);
      else ((float*)C)[idx] = v;
    }
  }
}

// ---------------------------------------------------------------------------
__global__ __launch_bounds__(256) void mk_softmax(float* __restrict__ scores, float scale)
{
  int row = (blockIdx.x << 2) + (threadIdx.x >> 6);
  int lane = threadIdx.x & 63;
  float* p = scores + (long)row * 256 + (lane << 2);
  float4 v = *(const float4*)p;
  float m = fmaxf(fmaxf(v.x, v.y), fmaxf(v.z, v.w));
#pragma unroll
  for (int o = 32; o; o >>= 1) m = fmaxf(m, __shfl_xor(m, o, 64));
  float sl = scale * LOG2E;
  v.x = fexp2(sl * (v.x - m));
  v.y = fexp2(sl * (v.y - m));
  v.z = fexp2(sl * (v.z - m));
  v.w = fexp2(sl * (v.w - m));
  float s = v.x + v.y + v.z + v.w;
#pragma unroll
  for (int o = 32; o; o >>= 1) s += __shfl_xor(s, o, 64);
  float r = 1.f / s;
  v.x *= r; v.y *= r; v.z *= r; v.w *= r;
  *(float4*)p = v;
}

// ---------------------------------------------------------------------------
__global__ __launch_bounds__(256) void mk_gates(const float* __restrict__ q2,
                                                const float* __restrict__ k2,
                                                float* __restrict__ gacc)
{
  __shared__ float k2p[8 * 808];
  int b = blockIdx.x >> 4, q = blockIdx.x & 15;
  for (int i = threadIdx.x; i < 6144; i += 256) {
    int e = i / 768, rem = i - e * 768;
    int h = rem / 96, j = rem - h * 96;
    k2p[e * 808 + h * 100 + j] = k2[i];
  }
  __syncthreads();
  const float scale = 0.10206207261596577f;
  int wid = threadIdx.x >> 6, lane = threadIdx.x & 63;
  int h = lane >> 3, e = lane & 7;
  const float* kp = &k2p[e * 808 + h * 100];
  float accL = 0.f;
#pragma unroll
  for (int ti = 0; ti < 4; ti++) {
    int l = q * 16 + wid * 4 + ti;
    const float* qh = q2 + ((long)b * LTOK + l) * DIMC + h * 96;
    float sum = 0.f;
#pragma unroll
    for (int j = 0; j < 96; j += 4) {
      float4 qv = *(const float4*)(qh + j);
      float4 kv = *(const float4*)(kp + j);
      sum += qv.x * kv.x + qv.y * kv.y + qv.z * kv.z + qv.w * kv.w;
    }
    float s = sum * scale;
    float mx = s;
#pragma unroll
    for (int o = 1; o <= 4; o <<= 1) mx = fmaxf(mx, __shfl_xor(mx, o, 64));
    float ex = fexp2((s - mx) * LOG2E);
    float se = ex;
#pragma unroll
    for (int o = 1; o <= 4; o <<= 1) se += __shfl_xor(se, o, 64);
    accL += ex / se;
  }
#pragma unroll
  for (int o = 8; o <= 32; o <<= 1) accL += __shfl_xor(accL, o, 64);
  __shared__ float red[4][8];
  if (lane < 8) red[wid][lane] = accL;
  __syncthreads();
  if (threadIdx.x < 8) {
    float v = red[0][threadIdx.x] + red[1][threadIdx.x] +
              red[2][threadIdx.x] + red[3][threadIdx.x];
    atomicAdd(&gacc[b * 8 + threadIdx.x], v);
  }
}

__global__ __launch_bounds__(64) void mk_gatetop(const float* __restrict__ gacc,
                                                 int* __restrict__ pe,
                                                 float* __restrict__ pw)
{
  int b = threadIdx.x;
  if (b >= 16) return;
  float g[8];
  for (int e = 0; e < 8; e++) g[e] = gacc[b * 8 + e] * (1.f / (8.f * 256.f));
  float mx = g[0];
  for (int e = 1; e < 8; e++) mx = fmaxf(mx, g[e]);
  float se = 0.f;
  for (int e = 0; e < 8; e++) { g[e] = expf(g[e] - mx); se += g[e]; }
  for (int e = 0; e < 8; e++) g[e] /= se;
  int i0 = 0;
  for (int e = 1; e < 8; e++) if (g[e] > g[i0]) i0 = e;
  int i1 = (i0 == 0) ? 1 : 0;
  for (int e = 0; e < 8; e++) if (e != i0 && g[e] > g[i1]) i1 = e;
  float w0 = 1.f / (1.f + expf(g[i1] - g[i0]));
  pe[2 * b] = i0; pe[2 * b + 1] = i1;
  pw[2 * b] = w0; pw[2 * b + 1] = 1.f - w0;
}

// ---------------------------------------------------------------------------
// Depthwise 3x3 conv + bias + SiLU, split xz_x (stride 768).
// ---------------------------------------------------------------------------
__global__ __launch_bounds__(768) void mk_conv(const float* __restrict__ xzx,
                                               const float* __restrict__ cw,
                                               const float* __restrict__ cb,
                                               const int* __restrict__ pe,
                                               float* __restrict__ xc)
{
  int blk = blockIdx.x;
  int p = blk >> 8, t = blk & 255;
  int e = pe[p];
  int h = t >> 4, w = t & 15;
  int c = threadIdx.x;
  const float* wp = cw + ((long)e * DIMC + c) * 9;
  float acc = cb[e * DIMC + c];
#pragma unroll
  for (int dh = 0; dh < 3; dh++) {
    int hh = h + dh - 1;
    if (hh < 0 || hh > 15) continue;
#pragma unroll
    for (int dw = 0; dw < 3; dw++) {
      int ww = w + dw - 1;
      if (ww < 0 || ww > 15) continue;
      acc += xzx[((long)p * LTOK + hh * 16 + ww) * DIMC + c] * wp[dh * 3 + dw];
    }
  }
  xc[((long)p * LTOK + t) * DIMC + c] = acc / (1.f + fexp2(-acc * LOG2E));
}

__device__ __forceinline__ int tmap(int dir, int s) {
  if (dir == 0) return s;
  if (dir == 1) return 255 - s;
  if (dir == 2) return ((s & 15) << 4) | (s >> 4);
  int u = 255 - s;
  return ((u & 15) << 4) | (u >> 4);
}

// ---------------------------------------------------------------------------
__global__ __launch_bounds__(256) void mk_dbl(const float* __restrict__ xc,
                                              const float* __restrict__ xproj,
                                              const int* __restrict__ pe,
                                              float* __restrict__ dblm)
{
  int p = blockIdx.x >> 2, q = blockIdx.x & 3;
  int e = pe[p];
  int tl = threadIdx.x & 63;
  int dir = threadIdx.x >> 6;
  int m = q * 64 + tl;
  const float* xr = xc + ((long)p * LTOK + m) * DIMC;
  const float* wbase = xproj + (long)(e * 4 + dir) * 6 * DIMC;
  float s[6] = {0.f, 0.f, 0.f, 0.f, 0.f, 0.f};
  for (int c = 0; c < DIMC; c += 4) {
    float4 xv = *(const float4*)(xr + c);
#pragma unroll
    for (int j = 0; j < 6; j++) {
      float4 wv = *(const float4*)(wbase + j * DIMC + c);
      s[j] += xv.x * wv.x + xv.y * wv.y + xv.z * wv.z + xv.w * wv.w;
    }
  }
  float* o = dblm + ((long)p * LTOK + m) * 24 + dir * 6;
#pragma unroll
  for (int j = 0; j < 6; j++) o[j] = s[j];
}

// ---------------------------------------------------------------------------
// Fused selective scan: block = (p, 16-ch group), 512 thr = 4dir x 8seg x 16c.
// Phase 1: per-thread 32-token segment scan from h=0, dec/u cached in VGPRs,
//   HW exp2/log2 softplus+decay. Publishes (prod dec, h_local) to LDS.
// Phase 2: h_init combine from LDS (<=7 fma). Phase 3: register replay with
//   LDS-atomic direction merge. Epilogue: coalesced write, D-term folded.
// ---------------------------------------------------------------------------
__global__ __launch_bounds__(512) void mk_scan(const float* __restrict__ xc,
                                               const float* __restrict__ dblm,
                                               const float* __restrict__ dtw,
                                               const float* __restrict__ dtb,
                                               const float* __restrict__ Alog,
                                               const float* __restrict__ Dp,
                                               const int* __restrict__ pe,
                                               float* __restrict__ yac)
{
  __shared__ float yS[256 * 17];   // 17408 B
  __shared__ float aS[32][16];     // (dir*8+seg, c) segment decay products
  __shared__ float hS[32][16];     // (dir*8+seg, c) segment local h
  __shared__ float cS[4][256];     // C coefficient per (dir, token m)
  __shared__ float dsum[16];
  int blk = blockIdx.x;
  int p = blk / 48, cg = blk - p * 48;
  int c0 = cg << 4;
  int e = pe[p];
  int tid = threadIdx.x;
  for (int i = tid; i < 256 * 17; i += 512) yS[i] = 0.f;
  for (int i = tid; i < 1024; i += 512) {
    int dd = i >> 8, mt = i & 255;
    cS[dd][mt] = dblm[((long)p * LTOK + mt) * 24 + dd * 6 + 5];
  }
  if (tid < 16) {
    float s = 0.f;
#pragma unroll
    for (int dd = 0; dd < 4; dd++) s += Dp[(long)(e * 4 + dd) * DIMC + c0 + tid];
    dsum[tid] = s;
  }
  __syncthreads();

  int c = tid & 15;
  int rr = tid >> 4;
  int seg = rr & 7;
  int dir = rr >> 3;
  int d = c0 + c;
  const float* xcp = xc + (long)p * LTOK * DIMC;
  const float* dbp = dblm + (long)p * LTOK * 24 + dir * 6;
  long pb = (long)(e * 4 + dir) * DIMC + d;
  float4 wv = *(const float4*)(dtw + pb * 4);
  float bdt = dtb[pb];
  float Ad = -fexp2(Alog[pb] * LOG2E);
  float dec[32], u[32];
  float h = 0.f, ap = 1.f;
  int t0 = seg << 5;
#pragma unroll
  for (int tb = 0; tb < 32; tb += 8) {
#pragma unroll
    for (int i = 0; i < 8; i++) {
      int t = t0 + tb + i;
      int m = tmap(dir, t);
      const float* db = dbp + (long)m * 24;
      float2 d01 = *(const float2*)(db);
      float2 d23 = *(const float2*)(db + 2);
      float bq = db[4];
      float xr = wv.x * d01.x + wv.y * d01.y + wv.z * d23.x + wv.w * d23.y + bdt;
      // softplus + decay via exp2/log2: g = log2(1+2^(xr*log2e));
      // dt = g*ln2; dec = e^(Ad*dt) = 2^(g*Ad)
      float te = fexp2(xr * LOG2E);
      float g = flog2(1.f + te);
      g = (xr > 60.f) ? xr * LOG2E : g;
      float dt = g * LN2;
      float de = fexp2(g * Ad);
      float xv = xcp[(long)m * DIMC + d];
      dec[tb + i] = de;
      u[tb + i] = dt * xv * bq;
      h = de * h + u[tb + i];
      ap *= de;
    }
  }
  aS[dir * 8 + seg][c] = ap;
  hS[dir * 8 + seg][c] = h;
  __syncthreads();

  float hh = 0.f;
  for (int j = 0; j < seg; j++)
    hh = aS[dir * 8 + j][c] * hh + hS[dir * 8 + j][c];

#pragma unroll
  for (int tb = 0; tb < 32; tb += 8) {
#pragma unroll
    for (int i = 0; i < 8; i++) {
      int t = t0 + tb + i;
      int m = tmap(dir, t);
      hh = dec[tb + i] * hh + u[tb + i];
      atomicAdd(&yS[m * 17 + c], hh * cS[dir][m]);
    }
  }
  __syncthreads();

  float* yp = yac + (long)p * LTOK * DIMC + c0;
  for (int i = tid; i < 256 * 16; i += 512) {
    int t = i >> 4, cz = i & 15;
    yp[(long)t * DIMC + cz] = yS[t * 17 + cz] + xcp[(long)t * DIMC + c0 + cz] * dsum[cz];
  }
}

// ---------------------------------------------------------------------------
__global__ __launch_bounds__(768) void mk_lnfin(const float* __restrict__ yac,
                                                const float* __restrict__ xzz,
                                                const float* __restrict__ lns,
                                                const float* __restrict__ lnb,
                                                const int* __restrict__ pe,
                                                float* __restrict__ eo)
{
  int p = blockIdx.x;
  int e = pe[p];
  int tid = threadIdx.x;
  int wid = tid >> 6, lane = tid & 63;
  float ls[12], lb[12], acc[12];
#pragma unroll
  for (int i = 0; i < 12; i++) {
    int d = i * 64 + lane;
    ls[i] = lns[e * DIMC + d];
    lb[i] = lnb[e * DIMC + d];
    acc[i] = 0.f;
  }
  for (int t = wid; t < 256; t += 12) {
    const float* yr = yac + ((long)p * LTOK + t) * DIMC;
    const float* zr = xzz + ((long)p * LTOK + t) * DIMC;
    float v[12];
    float s = 0.f;
#pragma unroll
    for (int i = 0; i < 12; i++) { v[i] = yr[i * 64 + lane]; s += v[i]; }
#pragma unroll
    for (int o = 32; o; o >>= 1) s += __shfl_xor(s, o, 64);
    float mu = s * (1.f / 768.f);
    float sq = 0.f;
#pragma unroll
    for (int i = 0; i < 12; i++) { float dlt = v[i] - mu; sq += dlt * dlt; }
#pragma unroll
    for (int o = 32; o; o >>= 1) sq += __shfl_xor(sq, o, 64);
    float rs = rsqrtf(sq * (1.f / 768.f) + 1e-5f);
#pragma unroll
    for (int i = 0; i < 12; i++) {
      float y = (v[i] - mu) * rs * ls[i] + lb[i];
      float z = zr[i * 64 + lane];
      y *= z / (1.f + fexp2(-z * LOG2E));
      acc[i] += y;
    }
  }
  __shared__ float sacc[768];
  sacc[tid] = 0.f;
  __syncthreads();
#pragma unroll
  for (int i = 0; i < 12; i++) atomicAdd(&sacc[i * 64 + lane], acc[i]);
  __syncthreads();
  eo[(long)p * DIMC + tid] = sacc[tid] * (1.f / 256.f);
}

__global__ __launch_bounds__(768) void mk_out(const float* __restrict__ eo,
                                              const float* __restrict__ pw,
                                              float* __restrict__ out)
{
  int b = blockIdx.x, d = threadIdx.x;
  float v = pw[2 * b] * eo[(long)(2 * b) * DIMC + d] +
            pw[2 * b + 1] * eo[(long)(2 * b + 1) * DIMC + d];
  out[b * DIMC + d] = v;
}

// ---------------------------------------------------------------------------
extern "C" void kernel_launch(void* const* d_in, const int* in_sizes, int n_in,
                              void* d_out, int out_size, void* d_ws, size_t ws_size,
                              hipStream_t stream)
{
  const float* x        = (const float*)d_in[0];
  const float* sa_in_w  = (const float*)d_in[1];
  const float* sa_in_b  = (const float*)d_in[2];
  const float* sa_out_w = (const float*)d_in[3];
  const float* sa_out_b = (const float*)d_in[4];
  const float* ca_in_w  = (const float*)d_in[5];
  const float* ca_in_b  = (const float*)d_in[6];
  const float* eq       = (const float*)d_in[7];
  const float* e_in_w   = (const float*)d_in[8];
  const float* e_in_b   = (const float*)d_in[9];
  const float* e_conv_w = (const float*)d_in[10];
  const float* e_conv_b = (const float*)d_in[11];
  const float* e_xproj  = (const float*)d_in[12];
  const float* e_dtw    = (const float*)d_in[13];
  const float* e_dtb    = (const float*)d_in[14];
  const float* e_Alog   = (const float*)d_in[15];
  const float* e_D      = (const float*)d_in[16];
  const float* e_lns    = (const float*)d_in[17];
  const float* e_lnb    = (const float*)d_in[18];
  float* out = (float*)d_out;

  float* ws = (float*)d_ws;
  // ---- attention phase ----
  float*   qkv    = ws + 0;                      // 0 .. 9,437,184
  float*   scores = ws + 9437184;                // .. 17,825,792
  ushortt* ctxa_b = (ushortt*)(ws + 17825792);   // .. 19,398,656
  ushortt* xb     = (ushortt*)(ws + 20971520);   // .. 22,544,384
  ushortt* wqkv_b = (ushortt*)(ws + 22544384);   // .. 23,429,120
  ushortt* saow_b = (ushortt*)(ws + 23429120);   // .. 23,724,032
  ushortt* caw_b  = (ushortt*)(ws + 23724032);   // .. 24,018,944
  ushortt* ctx_b  = (ushortt*)(ws + 3145728);    // (in dead qkv)
  float*   q2     = ws + 4718592;                // (in dead qkv)
  // ---- persistent smalls ----
  float*   k2     = ws + 25165824;
  int*     pe     = (int*)(ws + 25171968);
  float*   pw     = ws + 25172000;
  float*   eo     = ws + 25172032;               // .. 25,196,608
  float*   dblm   = ws + 25196608;               // .. 25,393,216
  float*   gacc   = ws + 25393216;               // .. 25,393,344 (peak 101.6MB)
  // ---- expert phase (attention regions dead) ----
  float*   xz_x   = ws + 0;                      // .. 6,291,456
  float*   xz_z   = ws + 6291456;                // .. 12,582,912 (live -> lnfin)
  ushortt* ew_b   = (ushortt*)(ws + 12582912);   // (dead scores region)
  float*   xc     = ws + 12582912;               // .. 18,874,368 (after ew_b dead)
  float*   yac    = ws + 18874368;               // .. 25,165,824

  const float scale = 0.10206207261596577f;

  // 0. fused upfront casts: x, sa_in_w, sa_out_w, ca_in_w[:768]
  mk_mcast4<<<5952, 256, 0, stream>>>(x, xb, sa_in_w, wqkv_b, sa_out_w, saow_b,
                                      ca_in_w, caw_b);
  // 1. qkv = x @ sa_in_w^T + b  (4096x2304x768 MFMA, fp32 out)
  mk_mfma<<<dim3(32 * 18, 1), 256, 0, stream>>>(xb, wqkv_b, sa_in_b, qkv,
      768, 768, 768, 2304, 0, 0, 0, 0, nullptr, 18, 0, 1 << 30, nullptr, 0);
  // 2. scores = q @ k^T  (256x256x96, Z=128)
  mk_gemm<<<dim3(16, 128), 256, 0, stream>>>(qkv, qkv + 768, nullptr, scores,
      256, 256, 96, 2304, 2304, 256, 8, 589824, 96, 589824, 96, 524288, 65536, 1, 4, 0);
  // 3. softmax
  mk_softmax<<<8192, 256, 0, stream>>>(scores, scale);
  // 4. ctxa = att @ v  -> bf16 directly
  mk_gemm<<<dim3(8, 128), 256, 0, stream>>>(scores, qkv + 1536, nullptr, ctxa_b,
      256, 96, 256, 256, 2304, 768, 8, 524288, 65536, 589824, 96, 196608, 96, 0, 2, 1);
  // 4b. cast expert weights into dead scores region
  mk_cast<<<9216, 256, 0, stream>>>(e_in_w, ew_b, 9437184);
  // 5. ctx = ctxa @ sa_out_w^T + b -> bf16 (4096x768x768 MFMA)
  mk_mfma<<<dim3(32 * 6, 1), 256, 0, stream>>>(ctxa_b, saow_b, sa_out_b, ctx_b,
      768, 768, 768, 768, 0, 0, 0, 0, nullptr, 6, 1, 1 << 30, nullptr, 0);
  // 6. q2 = ctx @ ca_in_w[:768]^T + b (fp32 out)
  mk_mfma<<<dim3(32 * 6, 1), 256, 0, stream>>>(ctx_b, caw_b, ca_in_b, q2,
      768, 768, 768, 768, 0, 0, 0, 0, nullptr, 6, 0, 1 << 30, nullptr, 0);
  // 7. k2 = eq @ ca_in_w[768:]^T + b  (8x768x768 fp32)
  mk_gemm<<<dim3(12, 1), 256, 0, stream>>>(eq, ca_in_w + 589824, ca_in_b + 768, k2,
      8, 768, 768, 768, 768, 768, 1, 0, 0, 0, 0, 0, 0, 1, 12, 0);
  // 8. gate
  (void)hipMemsetAsync(gacc, 0, 128 * sizeof(float), stream);
  mk_gates<<<256, 256, 0, stream>>>(q2, k2, gacc);
  mk_gatetop<<<1, 64, 0, stream>>>(gacc, pe, pw);
  // 9. xz = x @ e_in_w[e]^T + b (256x1536x768, Z=32) split -> xz_x | xz_z
  mk_mfma<<<dim3(2 * 12, 32), 256, 0, stream>>>(xb, ew_b, e_in_b, xz_x,
      768, 768, 768, 768, 196608, 1179648, 196608, 1536, pe, 12, 0, 768, xz_z, 768);
  // 10. depthwise conv + SiLU
  mk_conv<<<32 * 256, 768, 0, stream>>>(xz_x, e_conv_w, e_conv_b, pe, xc);
  // 11. dblm projections
  mk_dbl<<<128, 256, 0, stream>>>(xc, e_xproj, pe, dblm);
  // 12. fused segmented scan (single kernel, register replay)
  mk_scan<<<1536, 512, 0, stream>>>(xc, dblm, e_dtw, e_dtb, e_Alog, e_D, pe, yac);
  // 13. LN + silu(z) + token mean
  mk_lnfin<<<32, 768, 0, stream>>>(yac, xz_z, e_lns, e_lnb, pe, eo);
  // 14. weighted top-2 combine
  mk_out<<<16, 768, 0, stream>>>(eo, pw, out);

  (void)in_sizes; (void)n_in; (void)out_size; (void)ws_size;
}

// Round 10
// 708.443 us; speedup vs baseline: 1.2102x; 1.1044x over previous
//
#include <hip/hip_runtime.h>
#include <hip/hip_bf16.h>

// MoEFSCIL: B=16, H=W=16, L=256, DIM=768, NH=8, HD=96, NEXP=8, TOPK=2.
// fp32 in/out. Big GEMMs bf16 MFMA; attention fp32.
// Scan v5: no register replay (recompute w/ HW exp2/log2), dblm staged in
// LDS, 46KB LDS -> 3 blocks/CU. dbl: wave-per-token coalesced.

#define LTOK 256
#define DIMC 768

typedef unsigned short ushortt;
typedef __attribute__((ext_vector_type(8))) short bf16x8;
typedef __attribute__((ext_vector_type(4))) float f32x4;

#define LOG2E 1.44269504f
#define LN2   0.69314718f

__device__ __forceinline__ float fexp2(float x) { return __builtin_amdgcn_exp2f(x); }
__device__ __forceinline__ float flog2(float x) { return __builtin_amdgcn_logf(x); }

__device__ __forceinline__ ushortt f2b(float f) {
  union { float f; unsigned u; } c; c.f = f;
  unsigned r = (c.u + 0x7FFFu + ((c.u >> 16) & 1u)) >> 16;
  return (ushortt)r;
}

// ---------------------------------------------------------------------------
// Fused 4-tensor fp32->bf16 cast (x, sa_in_w, sa_out_w, ca_in_w[:768] rows).
// ---------------------------------------------------------------------------
__global__ __launch_bounds__(256) void mk_mcast4(
    const float* __restrict__ s0, ushortt* __restrict__ d0,
    const float* __restrict__ s1, ushortt* __restrict__ d1,
    const float* __restrict__ s2, ushortt* __restrict__ d2,
    const float* __restrict__ s3, ushortt* __restrict__ d3)
{
  long g = (long)blockIdx.x * 256 + threadIdx.x;   // float4 chunk id
  const float* s; ushortt* dst; long o;
  if (g < 786432)       { s = s0; dst = d0; o = g; }
  else if (g < 1228800) { s = s1; dst = d1; o = g - 786432; }
  else if (g < 1376256) { s = s2; dst = d2; o = g - 1228800; }
  else                  { s = s3; dst = d3; o = g - 1376256; }
  o <<= 2;
  float4 v = *(const float4*)(s + o);
  ushort4 w;
  w.x = f2b(v.x); w.y = f2b(v.y); w.z = f2b(v.z); w.w = f2b(v.w);
  *(ushort4*)(dst + o) = w;
}

__global__ __launch_bounds__(256) void mk_cast(const float* __restrict__ in,
                                               ushortt* __restrict__ outp, long n)
{
  long i = ((long)blockIdx.x * 256 + threadIdx.x) * 4;
  if (i + 3 < n) {
    float4 v = *(const float4*)(in + i);
    ushort4 o;
    o.x = f2b(v.x); o.y = f2b(v.y); o.z = f2b(v.z); o.w = f2b(v.w);
    *(ushort4*)(outp + i) = o;
  }
}

// ---------------------------------------------------------------------------
// bf16 MFMA GEMM: C[z] = A[z](M,K) @ B[z](N,K)^T + bias.
// ---------------------------------------------------------------------------
__global__ __launch_bounds__(256) void mk_mfma(
    const ushortt* __restrict__ A, const ushortt* __restrict__ B,
    const float* __restrict__ bias, void* __restrict__ C,
    int K, int lda, int ldb, int ldc,
    long sA, long sB, long sC, long sBias,
    const int* __restrict__ pairExp, int tilesN,
    int outBf, int splitN, void* __restrict__ C2, int ldc2)
{
  int z = blockIdx.y;
  long aoff = 0, boff = 0, coff = 0, biasoff = 0;
  if (pairExp) {
    int e = pairExp[z];
    aoff = (long)(z >> 1) * sA; boff = (long)e * sB;
    coff = (long)z * sC; biasoff = (long)e * sBias;
  }
  int tile = blockIdx.x;
  int tm = tile / tilesN, tn = tile - tm * tilesN;
  long m0 = (long)tm << 7, n0 = (long)tn << 7;

  __shared__ ushortt As[128][40];
  __shared__ ushortt Bs[128][40];

  int tid = threadIdx.x;
  int lane = tid & 63, wvi = tid >> 6;
  int wr = wvi >> 1, wc = wvi & 1;
  int lm = lane & 15, lg = lane >> 4;

  f32x4 zero4 = {0.f, 0.f, 0.f, 0.f};
  f32x4 acc[4][4];
#pragma unroll
  for (int i = 0; i < 4; i++)
#pragma unroll
    for (int j = 0; j < 4; j++) acc[i][j] = zero4;

  const ushortt* Ab = A + aoff;
  const ushortt* Bb = B + boff;

  for (int k0 = 0; k0 < K; k0 += 32) {
#pragma unroll
    for (int h = 0; h < 2; h++) {
      int q = tid + h * 256;
      int row = q >> 2, ck = (q & 3) << 3;
      *(uint4*)&As[row][ck] = *(const uint4*)(Ab + (m0 + row) * lda + k0 + ck);
      *(uint4*)&Bs[row][ck] = *(const uint4*)(Bb + (n0 + row) * ldb + k0 + ck);
    }
    __syncthreads();
    bf16x8 af[4], bfr[4];
#pragma unroll
    for (int i = 0; i < 4; i++)
      af[i] = *(const bf16x8*)&As[wr * 64 + i * 16 + lm][lg << 3];
#pragma unroll
    for (int j = 0; j < 4; j++)
      bfr[j] = *(const bf16x8*)&Bs[wc * 64 + j * 16 + lm][lg << 3];
#pragma unroll
    for (int i = 0; i < 4; i++)
#pragma unroll
      for (int j = 0; j < 4; j++)
        acc[i][j] = __builtin_amdgcn_mfma_f32_16x16x32_bf16(af[i], bfr[j], acc[i][j], 0, 0, 0);
    __syncthreads();
  }

#pragma unroll
  for (int mt = 0; mt < 4; mt++) {
#pragma unroll
    for (int nt = 0; nt < 4; nt++) {
      long grow = m0 + wr * 64 + mt * 16 + lg * 4;
      long gcol = n0 + wc * 64 + nt * 16 + lm;
      float bv = bias ? bias[biasoff + gcol] : 0.f;
      void* Ct; long col; int ld;
      if ((int)gcol < splitN) { Ct = C; col = gcol; ld = ldc; }
      else { Ct = C2; col = gcol - splitN; ld = ldc2; }
#pragma unroll
      for (int r = 0; r < 4; r++) {
        float v = acc[mt][nt][r] + bv;
        long idx = coff + (grow + r) * ld + col;
        if (outBf) ((ushortt*)Ct)[idx] = f2b(v);
        else ((float*)Ct)[idx] = v;
      }
    }
  }
}

// ---------------------------------------------------------------------------
// fp32 batched GEMM (attention + k2). outBf: bf16 store.
// ---------------------------------------------------------------------------
__global__ __launch_bounds__(256) void mk_gemm(
    const float* __restrict__ A, const float* __restrict__ B,
    const float* __restrict__ bias, void* __restrict__ C,
    int M, int N, int K, int lda, int ldb, int ldc,
    int zdiv,
    long sA1, long sA2, long sB1, long sB2, long sC1, long sC2,
    int bIsNT, int tilesN, int outBf)
{
  int z = blockIdx.y;
  int z1 = z / zdiv, z2 = z - z1 * zdiv;
  const float* Ab = A + (long)z1 * sA1 + (long)z2 * sA2;
  const float* Bb = B + (long)z1 * sB1 + (long)z2 * sB2;
  long coff = (long)z1 * sC1 + (long)z2 * sC2;

  int tile = blockIdx.x;
  int tm = tile / tilesN, tn = tile - tm * tilesN;
  int m0 = tm << 6, n0 = tn << 6;

  __shared__ float As[16][68];
  __shared__ float Bs[16][68];

  int tid = threadIdx.x;
  int tx = tid & 15, ty = tid >> 4;
  int lrow = tid >> 2;
  int lk = (tid & 3) << 2;
  int bkk = tid >> 4;
  int bnn = (tid & 15) << 2;

  float acc[4][4];
#pragma unroll
  for (int i = 0; i < 4; i++)
#pragma unroll
    for (int j = 0; j < 4; j++) acc[i][j] = 0.f;

  for (int k0 = 0; k0 < K; k0 += 16) {
    {
      int gm = m0 + lrow;
      float4 v = {0.f, 0.f, 0.f, 0.f};
      if (gm < M) v = *(const float4*)(Ab + (long)gm * lda + (k0 + lk));
      As[lk + 0][lrow] = v.x; As[lk + 1][lrow] = v.y;
      As[lk + 2][lrow] = v.z; As[lk + 3][lrow] = v.w;
    }
    if (bIsNT) {
      int gn = n0 + lrow;
      float4 v = {0.f, 0.f, 0.f, 0.f};
      if (gn < N) v = *(const float4*)(Bb + (long)gn * ldb + (k0 + lk));
      Bs[lk + 0][lrow] = v.x; Bs[lk + 1][lrow] = v.y;
      Bs[lk + 2][lrow] = v.z; Bs[lk + 3][lrow] = v.w;
    } else {
      int gn = n0 + bnn;
      float4 v = {0.f, 0.f, 0.f, 0.f};
      if (gn + 3 < N) {
        v = *(const float4*)(Bb + (long)(k0 + bkk) * ldb + gn);
      } else {
        float t0 = (gn + 0 < N) ? Bb[(long)(k0 + bkk) * ldb + gn + 0] : 0.f;
        float t1 = (gn + 1 < N) ? Bb[(long)(k0 + bkk) * ldb + gn + 1] : 0.f;
        float t2 = (gn + 2 < N) ? Bb[(long)(k0 + bkk) * ldb + gn + 2] : 0.f;
        float t3 = (gn + 3 < N) ? Bb[(long)(k0 + bkk) * ldb + gn + 3] : 0.f;
        v.x = t0; v.y = t1; v.z = t2; v.w = t3;
      }
      *(float4*)&Bs[bkk][bnn] = v;
    }
    __syncthreads();
#pragma unroll
    for (int kk = 0; kk < 16; kk++) {
      float4 a = *(const float4*)&As[kk][ty << 2];
      float4 b = *(const float4*)&Bs[kk][tx << 2];
      acc[0][0] += a.x * b.x; acc[0][1] += a.x * b.y; acc[0][2] += a.x * b.z; acc[0][3] += a.x * b.w;
      acc[1][0] += a.y * b.x; acc[1][1] += a.y * b.y; acc[1][2] += a.y * b.z; acc[1][3] += a.y * b.w;
      acc[2][0] += a.z * b.x; acc[2][1] += a.z * b.y; acc[2][2] += a.z * b.z; acc[2][3] += a.z * b.w;
      acc[3][0] += a.w * b.x; acc[3][1] += a.w * b.y; acc[3][2] += a.w * b.z; acc[3][3] += a.w * b.w;
    }
    __syncthreads();
  }

#pragma unroll
  for (int i = 0; i < 4; i++) {
    int gm = m0 + (ty << 2) + i;
    if (gm >= M) continue;
#pragma unroll
    for (int j = 0; j < 4; j++) {
      int gn = n0 + (tx << 2) + j;
      if (gn >= N) continue;
      float v = acc[i][j];
      if (bias) v += bias[gn];
      long idx = coff + (long)gm * ldc + gn;
      if (outBf) ((ushortt*)C)[idx] = f2b(v);
      else ((float*)C)[idx] = v;
    }
  }
}

// ---------------------------------------------------------------------------
__global__ __launch_bounds__(256) void mk_softmax(float* __restrict__ scores, float scale)
{
  int row = (blockIdx.x << 2) + (threadIdx.x >> 6);
  int lane = threadIdx.x & 63;
  float* p = scores + (long)row * 256 + (lane << 2);
  float4 v = *(const float4*)p;
  float m = fmaxf(fmaxf(v.x, v.y), fmaxf(v.z, v.w));
#pragma unroll
  for (int o = 32; o; o >>= 1) m = fmaxf(m, __shfl_xor(m, o, 64));
  float sl = scale * LOG2E;
  v.x = fexp2(sl * (v.x - m));
  v.y = fexp2(sl * (v.y - m));
  v.z = fexp2(sl * (v.z - m));
  v.w = fexp2(sl * (v.w - m));
  float s = v.x + v.y + v.z + v.w;
#pragma unroll
  for (int o = 32; o; o >>= 1) s += __shfl_xor(s, o, 64);
  float r = 1.f / s;
  v.x *= r; v.y *= r; v.z *= r; v.w *= r;
  *(float4*)p = v;
}

// ---------------------------------------------------------------------------
__global__ __launch_bounds__(256) void mk_gates(const float* __restrict__ q2,
                                                const float* __restrict__ k2,
                                                float* __restrict__ gacc)
{
  __shared__ float k2p[8 * 808];
  int b = blockIdx.x >> 4, q = blockIdx.x & 15;
  for (int i = threadIdx.x; i < 6144; i += 256) {
    int e = i / 768, rem = i - e * 768;
    int h = rem / 96, j = rem - h * 96;
    k2p[e * 808 + h * 100 + j] = k2[i];
  }
  __syncthreads();
  const float scale = 0.10206207261596577f;
  int wid = threadIdx.x >> 6, lane = threadIdx.x & 63;
  int h = lane >> 3, e = lane & 7;
  const float* kp = &k2p[e * 808 + h * 100];
  float accL = 0.f;
#pragma unroll
  for (int ti = 0; ti < 4; ti++) {
    int l = q * 16 + wid * 4 + ti;
    const float* qh = q2 + ((long)b * LTOK + l) * DIMC + h * 96;
    float sum = 0.f;
#pragma unroll
    for (int j = 0; j < 96; j += 4) {
      float4 qv = *(const float4*)(qh + j);
      float4 kv = *(const float4*)(kp + j);
      sum += qv.x * kv.x + qv.y * kv.y + qv.z * kv.z + qv.w * kv.w;
    }
    float s = sum * scale;
    float mx = s;
#pragma unroll
    for (int o = 1; o <= 4; o <<= 1) mx = fmaxf(mx, __shfl_xor(mx, o, 64));
    float ex = fexp2((s - mx) * LOG2E);
    float se = ex;
#pragma unroll
    for (int o = 1; o <= 4; o <<= 1) se += __shfl_xor(se, o, 64);
    accL += ex / se;
  }
#pragma unroll
  for (int o = 8; o <= 32; o <<= 1) accL += __shfl_xor(accL, o, 64);
  __shared__ float red[4][8];
  if (lane < 8) red[wid][lane] = accL;
  __syncthreads();
  if (threadIdx.x < 8) {
    float v = red[0][threadIdx.x] + red[1][threadIdx.x] +
              red[2][threadIdx.x] + red[3][threadIdx.x];
    atomicAdd(&gacc[b * 8 + threadIdx.x], v);
  }
}

__global__ __launch_bounds__(64) void mk_gatetop(const float* __restrict__ gacc,
                                                 int* __restrict__ pe,
                                                 float* __restrict__ pw)
{
  int b = threadIdx.x;
  if (b >= 16) return;
  float g[8];
  for (int e = 0; e < 8; e++) g[e] = gacc[b * 8 + e] * (1.f / (8.f * 256.f));
  float mx = g[0];
  for (int e = 1; e < 8; e++) mx = fmaxf(mx, g[e]);
  float se = 0.f;
  for (int e = 0; e < 8; e++) { g[e] = expf(g[e] - mx); se += g[e]; }
  for (int e = 0; e < 8; e++) g[e] /= se;
  int i0 = 0;
  for (int e = 1; e < 8; e++) if (g[e] > g[i0]) i0 = e;
  int i1 = (i0 == 0) ? 1 : 0;
  for (int e = 0; e < 8; e++) if (e != i0 && g[e] > g[i1]) i1 = e;
  float w0 = 1.f / (1.f + expf(g[i1] - g[i0]));
  pe[2 * b] = i0; pe[2 * b + 1] = i1;
  pw[2 * b] = w0; pw[2 * b + 1] = 1.f - w0;
}

// ---------------------------------------------------------------------------
// Depthwise 3x3 conv + bias + SiLU, split xz_x (stride 768).
// ---------------------------------------------------------------------------
__global__ __launch_bounds__(768) void mk_conv(const float* __restrict__ xzx,
                                               const float* __restrict__ cw,
                                               const float* __restrict__ cb,
                                               const int* __restrict__ pe,
                                               float* __restrict__ xc)
{
  int blk = blockIdx.x;
  int p = blk >> 8, t = blk & 255;
  int e = pe[p];
  int h = t >> 4, w = t & 15;
  int c = threadIdx.x;
  const float* wp = cw + ((long)e * DIMC + c) * 9;
  float acc = cb[e * DIMC + c];
#pragma unroll
  for (int dh = 0; dh < 3; dh++) {
    int hh = h + dh - 1;
    if (hh < 0 || hh > 15) continue;
#pragma unroll
    for (int dw = 0; dw < 3; dw++) {
      int ww = w + dw - 1;
      if (ww < 0 || ww > 15) continue;
      acc += xzx[((long)p * LTOK + hh * 16 + ww) * DIMC + c] * wp[dh * 3 + dw];
    }
  }
  xc[((long)p * LTOK + t) * DIMC + c] = acc / (1.f + fexp2(-acc * LOG2E));
}

__device__ __forceinline__ int tmap(int dir, int s) {
  if (dir == 0) return s;
  if (dir == 1) return 255 - s;
  if (dir == 2) return ((s & 15) << 4) | (s >> 4);
  int u = 255 - s;
  return ((u & 15) << 4) | (u >> 4);
}

// ---------------------------------------------------------------------------
// dbl v2: wave-per-token, lanes on channel dim (coalesced 1KB loads).
// Grid 2048 blocks x 256 thr (4 waves = 4 tokens). dblm[p][m][24] out.
// ---------------------------------------------------------------------------
__global__ __launch_bounds__(256) void mk_dbl(const float* __restrict__ xc,
                                              const float* __restrict__ xproj,
                                              const int* __restrict__ pe,
                                              float* __restrict__ dblm)
{
  int p = blockIdx.x >> 6;
  int tq = blockIdx.x & 63;
  int wid = threadIdx.x >> 6, lane = threadIdx.x & 63;
  int m = tq * 4 + wid;
  int e = pe[p];
  const float* xr = xc + ((long)p * LTOK + m) * DIMC;
  const float* wb = xproj + (long)e * 24 * DIMC;   // 24 rows (dir*6+j) x 768
  float4 xv[3];
#pragma unroll
  for (int j = 0; j < 3; j++) xv[j] = *(const float4*)(xr + j * 256 + lane * 4);
  float acc[24];
#pragma unroll
  for (int r = 0; r < 24; r++) {
    const float* wr = wb + r * DIMC;
    float s = 0.f;
#pragma unroll
    for (int j = 0; j < 3; j++) {
      float4 wv = *(const float4*)(wr + j * 256 + lane * 4);
      s += xv[j].x * wv.x + xv[j].y * wv.y + xv[j].z * wv.z + xv[j].w * wv.w;
    }
    acc[r] = s;
  }
#pragma unroll
  for (int r = 0; r < 24; r++)
#pragma unroll
    for (int o = 32; o; o >>= 1) acc[r] += __shfl_xor(acc[r], o, 64);
  if (lane == 0) {
    float* o = dblm + ((long)p * LTOK + m) * 24;
#pragma unroll
    for (int r = 0; r < 24; r++) o[r] = acc[r];
  }
}

// ---------------------------------------------------------------------------
// Scan v5: block = (p, 16-ch group), 512 thr = 4dir x 8seg x 16c.
// dblm tile staged in LDS (24KB); no register replay (phase 3 recomputes —
// HW exp2/log2 are cheap); low VGPR + 46KB LDS -> ~3 blocks/CU.
// ---------------------------------------------------------------------------
__global__ __launch_bounds__(512) void mk_scan(const float* __restrict__ xc,
                                               const float* __restrict__ dblm,
                                               const float* __restrict__ dtw,
                                               const float* __restrict__ dtb,
                                               const float* __restrict__ Alog,
                                               const float* __restrict__ Dp,
                                               const int* __restrict__ pe,
                                               float* __restrict__ yac)
{
  __shared__ float dbS[256 * 24];  // 24576 B
  __shared__ float yS[256 * 17];   // 17408 B
  __shared__ float aS[32][16];     // 2048 B
  __shared__ float hS[32][16];     // 2048 B
  __shared__ float dsum[16];
  int blk = blockIdx.x;
  int p = blk / 48, cg = blk - p * 48;
  int c0 = cg << 4;
  int e = pe[p];
  int tid = threadIdx.x;
  {
    const float4* src = (const float4*)(dblm + (long)p * LTOK * 24);
    float4* dst = (float4*)dbS;
    for (int i = tid; i < 1536; i += 512) dst[i] = src[i];
  }
  for (int i = tid; i < 256 * 17; i += 512) yS[i] = 0.f;
  if (tid < 16) {
    float s = 0.f;
#pragma unroll
    for (int dd = 0; dd < 4; dd++) s += Dp[(long)(e * 4 + dd) * DIMC + c0 + tid];
    dsum[tid] = s;
  }
  __syncthreads();

  int c = tid & 15;
  int rr = tid >> 4;              // rr = dir*8 + seg
  int seg = rr & 7;
  int dir = rr >> 3;
  int d = c0 + c;
  const float* xcp = xc + (long)p * LTOK * DIMC;
  long pb = (long)(e * 4 + dir) * DIMC + d;
  float4 wv = *(const float4*)(dtw + pb * 4);
  float bdt = dtb[pb];
  float Ad = -fexp2(Alog[pb] * LOG2E);
  int t0 = seg << 5;

  // phase 1: segment scan from h=0
  float h = 0.f, ap = 1.f;
  for (int tb = 0; tb < 32; tb += 8) {
    float xv[8]; int mm[8];
#pragma unroll
    for (int i = 0; i < 8; i++) {
      mm[i] = tmap(dir, t0 + tb + i);
      xv[i] = xcp[(long)mm[i] * DIMC + d];
    }
#pragma unroll
    for (int i = 0; i < 8; i++) {
      const float* db = &dbS[mm[i] * 24 + dir * 6];
      float xr = wv.x * db[0] + wv.y * db[1] + wv.z * db[2] + wv.w * db[3] + bdt;
      float te = fexp2(xr * LOG2E);
      float g = flog2(1.f + te);
      g = (xr > 60.f) ? xr * LOG2E : g;
      float de = fexp2(g * Ad);
      h = de * h + (g * LN2) * xv[i] * db[4];
      ap *= de;
    }
  }
  aS[rr][c] = ap;
  hS[rr][c] = h;
  __syncthreads();

  // phase 2: segment combine
  float hh = 0.f;
  for (int j = dir * 8; j < rr; j++)
    hh = aS[j][c] * hh + hS[j][c];

  // phase 3: recompute + emit via LDS atomic direction-merge
  for (int tb = 0; tb < 32; tb += 8) {
    float xv[8]; int mm[8];
#pragma unroll
    for (int i = 0; i < 8; i++) {
      mm[i] = tmap(dir, t0 + tb + i);
      xv[i] = xcp[(long)mm[i] * DIMC + d];
    }
#pragma unroll
    for (int i = 0; i < 8; i++) {
      const float* db = &dbS[mm[i] * 24 + dir * 6];
      float xr = wv.x * db[0] + wv.y * db[1] + wv.z * db[2] + wv.w * db[3] + bdt;
      float te = fexp2(xr * LOG2E);
      float g = flog2(1.f + te);
      g = (xr > 60.f) ? xr * LOG2E : g;
      float de = fexp2(g * Ad);
      hh = de * hh + (g * LN2) * xv[i] * db[4];
      atomicAdd(&yS[mm[i] * 17 + c], hh * db[5]);
    }
  }
  __syncthreads();

  float* yp = yac + (long)p * LTOK * DIMC + c0;
  for (int i = tid; i < 256 * 16; i += 512) {
    int t = i >> 4, cz = i & 15;
    yp[(long)t * DIMC + cz] = yS[t * 17 + cz] + xcp[(long)t * DIMC + c0 + cz] * dsum[cz];
  }
}

// ---------------------------------------------------------------------------
__global__ __launch_bounds__(768) void mk_lnfin(const float* __restrict__ yac,
                                                const float* __restrict__ xzz,
                                                const float* __restrict__ lns,
                                                const float* __restrict__ lnb,
                                                const int* __restrict__ pe,
                                                float* __restrict__ eo)
{
  int p = blockIdx.x;
  int e = pe[p];
  int tid = threadIdx.x;
  int wid = tid >> 6, lane = tid & 63;
  float ls[12], lb[12], acc[12];
#pragma unroll
  for (int i = 0; i < 12; i++) {
    int d = i * 64 + lane;
    ls[i] = lns[e * DIMC + d];
    lb[i] = lnb[e * DIMC + d];
    acc[i] = 0.f;
  }
  for (int t = wid; t < 256; t += 12) {
    const float* yr = yac + ((long)p * LTOK + t) * DIMC;
    const float* zr = xzz + ((long)p * LTOK + t) * DIMC;
    float v[12];
    float s = 0.f;
#pragma unroll
    for (int i = 0; i < 12; i++) { v[i] = yr[i * 64 + lane]; s += v[i]; }
#pragma unroll
    for (int o = 32; o; o >>= 1) s += __shfl_xor(s, o, 64);
    float mu = s * (1.f / 768.f);
    float sq = 0.f;
#pragma unroll
    for (int i = 0; i < 12; i++) { float dlt = v[i] - mu; sq += dlt * dlt; }
#pragma unroll
    for (int o = 32; o; o >>= 1) sq += __shfl_xor(sq, o, 64);
    float rs = rsqrtf(sq * (1.f / 768.f) + 1e-5f);
#pragma unroll
    for (int i = 0; i < 12; i++) {
      float y = (v[i] - mu) * rs * ls[i] + lb[i];
      float z = zr[i * 64 + lane];
      y *= z / (1.f + fexp2(-z * LOG2E));
      acc[i] += y;
    }
  }
  __shared__ float sacc[768];
  sacc[tid] = 0.f;
  __syncthreads();
#pragma unroll
  for (int i = 0; i < 12; i++) atomicAdd(&sacc[i * 64 + lane], acc[i]);
  __syncthreads();
  eo[(long)p * DIMC + tid] = sacc[tid] * (1.f / 256.f);
}

__global__ __launch_bounds__(768) void mk_out(const float* __restrict__ eo,
                                              const float* __restrict__ pw,
                                              float* __restrict__ out)
{
  int b = blockIdx.x, d = threadIdx.x;
  float v = pw[2 * b] * eo[(long)(2 * b) * DIMC + d] +
            pw[2 * b + 1] * eo[(long)(2 * b + 1) * DIMC + d];
  out[b * DIMC + d] = v;
}

// ---------------------------------------------------------------------------
extern "C" void kernel_launch(void* const* d_in, const int* in_sizes, int n_in,
                              void* d_out, int out_size, void* d_ws, size_t ws_size,
                              hipStream_t stream)
{
  const float* x        = (const float*)d_in[0];
  const float* sa_in_w  = (const float*)d_in[1];
  const float* sa_in_b  = (const float*)d_in[2];
  const float* sa_out_w = (const float*)d_in[3];
  const float* sa_out_b = (const float*)d_in[4];
  const float* ca_in_w  = (const float*)d_in[5];
  const float* ca_in_b  = (const float*)d_in[6];
  const float* eq       = (const float*)d_in[7];
  const float* e_in_w   = (const float*)d_in[8];
  const float* e_in_b   = (const float*)d_in[9];
  const float* e_conv_w = (const float*)d_in[10];
  const float* e_conv_b = (const float*)d_in[11];
  const float* e_xproj  = (const float*)d_in[12];
  const float* e_dtw    = (const float*)d_in[13];
  const float* e_dtb    = (const float*)d_in[14];
  const float* e_Alog   = (const float*)d_in[15];
  const float* e_D      = (const float*)d_in[16];
  const float* e_lns    = (const float*)d_in[17];
  const float* e_lnb    = (const float*)d_in[18];
  float* out = (float*)d_out;

  float* ws = (float*)d_ws;
  // ---- attention phase ----
  float*   qkv    = ws + 0;                      // 0 .. 9,437,184
  float*   scores = ws + 9437184;                // .. 17,825,792
  ushortt* ctxa_b = (ushortt*)(ws + 17825792);   // .. 19,398,656
  ushortt* xb     = (ushortt*)(ws + 20971520);   // .. 22,544,384
  ushortt* wqkv_b = (ushortt*)(ws + 22544384);   // .. 23,429,120
  ushortt* saow_b = (ushortt*)(ws + 23429120);   // .. 23,724,032
  ushortt* caw_b  = (ushortt*)(ws + 23724032);   // .. 24,018,944
  ushortt* ctx_b  = (ushortt*)(ws + 3145728);    // (in dead qkv)
  float*   q2     = ws + 4718592;                // (in dead qkv)
  // ---- persistent smalls ----
  float*   k2     = ws + 25165824;
  int*     pe     = (int*)(ws + 25171968);
  float*   pw     = ws + 25172000;
  float*   eo     = ws + 25172032;               // .. 25,196,608
  float*   dblm   = ws + 25196608;               // .. 25,393,216
  float*   gacc   = ws + 25393216;               // .. 25,393,344 (peak 101.6MB)
  // ---- expert phase (attention regions dead) ----
  float*   xz_x   = ws + 0;                      // .. 6,291,456
  float*   xz_z   = ws + 6291456;                // .. 12,582,912 (live -> lnfin)
  ushortt* ew_b   = (ushortt*)(ws + 12582912);   // (dead scores region)
  float*   xc     = ws + 12582912;               // .. 18,874,368 (after ew_b dead)
  float*   yac    = ws + 18874368;               // .. 25,165,824

  const float scale = 0.10206207261596577f;

  // 0. fused upfront casts: x, sa_in_w, sa_out_w, ca_in_w[:768]
  mk_mcast4<<<5952, 256, 0, stream>>>(x, xb, sa_in_w, wqkv_b, sa_out_w, saow_b,
                                      ca_in_w, caw_b);
  // 1. qkv = x @ sa_in_w^T + b  (4096x2304x768 MFMA, fp32 out)
  mk_mfma<<<dim3(32 * 18, 1), 256, 0, stream>>>(xb, wqkv_b, sa_in_b, qkv,
      768, 768, 768, 2304, 0, 0, 0, 0, nullptr, 18, 0, 1 << 30, nullptr, 0);
  // 2. scores = q @ k^T  (256x256x96, Z=128)
  mk_gemm<<<dim3(16, 128), 256, 0, stream>>>(qkv, qkv + 768, nullptr, scores,
      256, 256, 96, 2304, 2304, 256, 8, 589824, 96, 589824, 96, 524288, 65536, 1, 4, 0);
  // 3. softmax
  mk_softmax<<<8192, 256, 0, stream>>>(scores, scale);
  // 4. ctxa = att @ v  -> bf16 directly
  mk_gemm<<<dim3(8, 128), 256, 0, stream>>>(scores, qkv + 1536, nullptr, ctxa_b,
      256, 96, 256, 256, 2304, 768, 8, 524288, 65536, 589824, 96, 196608, 96, 0, 2, 1);
  // 4b. cast expert weights into dead scores region
  mk_cast<<<9216, 256, 0, stream>>>(e_in_w, ew_b, 9437184);
  // 5. ctx = ctxa @ sa_out_w^T + b -> bf16 (4096x768x768 MFMA)
  mk_mfma<<<dim3(32 * 6, 1), 256, 0, stream>>>(ctxa_b, saow_b, sa_out_b, ctx_b,
      768, 768, 768, 768, 0, 0, 0, 0, nullptr, 6, 1, 1 << 30, nullptr, 0);
  // 6. q2 = ctx @ ca_in_w[:768]^T + b (fp32 out)
  mk_mfma<<<dim3(32 * 6, 1), 256, 0, stream>>>(ctx_b, caw_b, ca_in_b, q2,
      768, 768, 768, 768, 0, 0, 0, 0, nullptr, 6, 0, 1 << 30, nullptr, 0);
  // 7. k2 = eq @ ca_in_w[768:]^T + b  (8x768x768 fp32)
  mk_gemm<<<dim3(12, 1), 256, 0, stream>>>(eq, ca_in_w + 589824, ca_in_b + 768, k2,
      8, 768, 768, 768, 768, 768, 1, 0, 0, 0, 0, 0, 0, 1, 12, 0);
  // 8. gate
  (void)hipMemsetAsync(gacc, 0, 128 * sizeof(float), stream);
  mk_gates<<<256, 256, 0, stream>>>(q2, k2, gacc);
  mk_gatetop<<<1, 64, 0, stream>>>(gacc, pe, pw);
  // 9. xz = x @ e_in_w[e]^T + b (256x1536x768, Z=32) split -> xz_x | xz_z
  mk_mfma<<<dim3(2 * 12, 32), 256, 0, stream>>>(xb, ew_b, e_in_b, xz_x,
      768, 768, 768, 768, 196608, 1179648, 196608, 1536, pe, 12, 0, 768, xz_z, 768);
  // 10. depthwise conv + SiLU
  mk_conv<<<32 * 256, 768, 0, stream>>>(xz_x, e_conv_w, e_conv_b, pe, xc);
  // 11. dbl projections (wave-per-token, coalesced)
  mk_dbl<<<2048, 256, 0, stream>>>(xc, e_xproj, pe, dblm);
  // 12. fused segmented scan v5
  mk_scan<<<1536, 512, 0, stream>>>(xc, dblm, e_dtw, e_dtb, e_Alog, e_D, pe, yac);
  // 13. LN + silu(z) + token mean
  mk_lnfin<<<32, 768, 0, stream>>>(yac, xz_z, e_lns, e_lnb, pe, eo);
  // 14. weighted top-2 combine
  mk_out<<<16, 768, 0, stream>>>(eo, pw, out);

  (void)in_sizes; (void)n_in; (void)out_size; (void)ws_size;
}

// Round 11
// 641.777 us; speedup vs baseline: 1.3359x; 1.1039x over previous
//
#include <hip/hip_runtime.h>
#include <hip/hip_bf16.h>

// MoEFSCIL: B=16, H=W=16, L=256, DIM=768, NH=8, HD=96, NEXP=8, TOPK=2.
// fp32 in/out. ALL GEMMs (incl. attention) bf16 MFMA; scan = fused segmented
// with LDS-staged dblm + HW exp2/log2; lnfin parallelized 512 blocks.

#define LTOK 256
#define DIMC 768

typedef unsigned short ushortt;
typedef __attribute__((ext_vector_type(8))) short bf16x8;
typedef __attribute__((ext_vector_type(4))) float f32x4;

#define LOG2E 1.44269504f
#define LN2   0.69314718f

__device__ __forceinline__ float fexp2(float x) { return __builtin_amdgcn_exp2f(x); }
__device__ __forceinline__ float flog2(float x) { return __builtin_amdgcn_logf(x); }

__device__ __forceinline__ ushortt f2b(float f) {
  union { float f; unsigned u; } c; c.f = f;
  unsigned r = (c.u + 0x7FFFu + ((c.u >> 16) & 1u)) >> 16;
  return (ushortt)r;
}

// ---------------------------------------------------------------------------
// Fused 4-tensor fp32->bf16 cast (x, sa_in_w, sa_out_w, ca_in_w[:768] rows).
// ---------------------------------------------------------------------------
__global__ __launch_bounds__(256) void mk_mcast4(
    const float* __restrict__ s0, ushortt* __restrict__ d0,
    const float* __restrict__ s1, ushortt* __restrict__ d1,
    const float* __restrict__ s2, ushortt* __restrict__ d2,
    const float* __restrict__ s3, ushortt* __restrict__ d3)
{
  long g = (long)blockIdx.x * 256 + threadIdx.x;   // float4 chunk id
  const float* s; ushortt* dst; long o;
  if (g < 786432)       { s = s0; dst = d0; o = g; }
  else if (g < 1228800) { s = s1; dst = d1; o = g - 786432; }
  else if (g < 1376256) { s = s2; dst = d2; o = g - 1228800; }
  else                  { s = s3; dst = d3; o = g - 1376256; }
  o <<= 2;
  float4 v = *(const float4*)(s + o);
  ushort4 w;
  w.x = f2b(v.x); w.y = f2b(v.y); w.z = f2b(v.z); w.w = f2b(v.w);
  *(ushort4*)(dst + o) = w;
}

__global__ __launch_bounds__(256) void mk_cast(const float* __restrict__ in,
                                               ushortt* __restrict__ outp, long n)
{
  long i = ((long)blockIdx.x * 256 + threadIdx.x) * 4;
  if (i + 3 < n) {
    float4 v = *(const float4*)(in + i);
    ushort4 o;
    o.x = f2b(v.x); o.y = f2b(v.y); o.z = f2b(v.z); o.w = f2b(v.w);
    *(ushort4*)(outp + i) = o;
  }
}

// ---------------------------------------------------------------------------
// bf16 MFMA GEMM: C[z] = A[z](M,K) @ B[z](N,K)^T + bias.
// Batch: pairExp (MoE) or zdiv (z1=z/zdiv, z2=z%zdiv) offsets.
// Column split at splitN: cols<splitN -> C (outBf), else C2 (outBf2, ldc2).
// c2vt: C2 written in vt layout [(b*8+h)*128 + j][t], b=row>>8, t=row&255,
//       h=(col-splitN)/96, j=(col-splitN)%96 (for the qkv v-transpose).
// ---------------------------------------------------------------------------
__global__ __launch_bounds__(256) void mk_mfma(
    const ushortt* __restrict__ A, const ushortt* __restrict__ B,
    const float* __restrict__ bias, void* __restrict__ C,
    int K, int lda, int ldb, int ldc,
    int zdiv, long sA1, long sA2, long sB1, long sB2, long sC1, long sC2,
    long sBias,
    const int* __restrict__ pairExp, int tilesN,
    int outBf, int splitN, void* __restrict__ C2, int ldc2, int outBf2, int c2vt)
{
  int z = blockIdx.y;
  long aoff, boff, coff, biasoff = 0;
  if (pairExp) {
    int e = pairExp[z];
    aoff = (long)(z >> 1) * sA1; boff = (long)e * sB1;
    coff = (long)z * sC1; biasoff = (long)e * sBias;
  } else {
    int z1 = z / zdiv, z2 = z - z1 * zdiv;
    aoff = (long)z1 * sA1 + (long)z2 * sA2;
    boff = (long)z1 * sB1 + (long)z2 * sB2;
    coff = (long)z1 * sC1 + (long)z2 * sC2;
  }
  int tile = blockIdx.x;
  int tm = tile / tilesN, tn = tile - tm * tilesN;
  long m0 = (long)tm << 7, n0 = (long)tn << 7;

  __shared__ ushortt As[128][40];
  __shared__ ushortt Bs[128][40];

  int tid = threadIdx.x;
  int lane = tid & 63, wvi = tid >> 6;
  int wr = wvi >> 1, wc = wvi & 1;
  int lm = lane & 15, lg = lane >> 4;

  f32x4 zero4 = {0.f, 0.f, 0.f, 0.f};
  f32x4 acc[4][4];
#pragma unroll
  for (int i = 0; i < 4; i++)
#pragma unroll
    for (int j = 0; j < 4; j++) acc[i][j] = zero4;

  const ushortt* Ab = A + aoff;
  const ushortt* Bb = B + boff;

  for (int k0 = 0; k0 < K; k0 += 32) {
#pragma unroll
    for (int h = 0; h < 2; h++) {
      int q = tid + h * 256;
      int row = q >> 2, ck = (q & 3) << 3;
      *(uint4*)&As[row][ck] = *(const uint4*)(Ab + (m0 + row) * lda + k0 + ck);
      *(uint4*)&Bs[row][ck] = *(const uint4*)(Bb + (n0 + row) * ldb + k0 + ck);
    }
    __syncthreads();
    bf16x8 af[4], bfr[4];
#pragma unroll
    for (int i = 0; i < 4; i++)
      af[i] = *(const bf16x8*)&As[wr * 64 + i * 16 + lm][lg << 3];
#pragma unroll
    for (int j = 0; j < 4; j++)
      bfr[j] = *(const bf16x8*)&Bs[wc * 64 + j * 16 + lm][lg << 3];
#pragma unroll
    for (int i = 0; i < 4; i++)
#pragma unroll
      for (int j = 0; j < 4; j++)
        acc[i][j] = __builtin_amdgcn_mfma_f32_16x16x32_bf16(af[i], bfr[j], acc[i][j], 0, 0, 0);
    __syncthreads();
  }

#pragma unroll
  for (int mt = 0; mt < 4; mt++) {
#pragma unroll
    for (int nt = 0; nt < 4; nt++) {
      long grow = m0 + wr * 64 + mt * 16 + lg * 4;
      long gcol = n0 + wc * 64 + nt * 16 + lm;
      float bv = bias ? bias[biasoff + gcol] : 0.f;
      if ((int)gcol < splitN) {
#pragma unroll
        for (int r = 0; r < 4; r++) {
          float v = acc[mt][nt][r] + bv;
          long idx = coff + (grow + r) * ldc + gcol;
          if (outBf) ((ushortt*)C)[idx] = f2b(v);
          else ((float*)C)[idx] = v;
        }
      } else if (c2vt) {
        int cc = (int)gcol - splitN;            // 0..767
        int hh = cc / 96, jj = cc - hh * 96;
#pragma unroll
        for (int r = 0; r < 4; r++) {
          float v = acc[mt][nt][r] + bv;
          long gr = grow + r;
          long b = gr >> 8, t = gr & 255;
          long idx = (((b * 8 + hh) * 128 + jj) << 8) + t;
          ((ushortt*)C2)[idx] = f2b(v);
        }
      } else {
        long col = gcol - splitN;
#pragma unroll
        for (int r = 0; r < 4; r++) {
          float v = acc[mt][nt][r] + bv;
          long idx = coff + (grow + r) * ldc2 + col;
          if (outBf2) ((ushortt*)C2)[idx] = f2b(v);
          else ((float*)C2)[idx] = v;
        }
      }
    }
  }
}

// ---------------------------------------------------------------------------
// fp32 GEMM (k2 only now).
// ---------------------------------------------------------------------------
__global__ __launch_bounds__(256) void mk_gemm(
    const float* __restrict__ A, const float* __restrict__ B,
    const float* __restrict__ bias, float* __restrict__ C,
    int M, int N, int K, int lda, int ldb, int ldc, int tilesN)
{
  int tile = blockIdx.x;
  int tm = tile / tilesN, tn = tile - tm * tilesN;
  int m0 = tm << 6, n0 = tn << 6;

  __shared__ float As[16][68];
  __shared__ float Bs[16][68];

  int tid = threadIdx.x;
  int tx = tid & 15, ty = tid >> 4;
  int lrow = tid >> 2;
  int lk = (tid & 3) << 2;

  float acc[4][4];
#pragma unroll
  for (int i = 0; i < 4; i++)
#pragma unroll
    for (int j = 0; j < 4; j++) acc[i][j] = 0.f;

  for (int k0 = 0; k0 < K; k0 += 16) {
    {
      int gm = m0 + lrow;
      float4 v = {0.f, 0.f, 0.f, 0.f};
      if (gm < M) v = *(const float4*)(A + (long)gm * lda + (k0 + lk));
      As[lk + 0][lrow] = v.x; As[lk + 1][lrow] = v.y;
      As[lk + 2][lrow] = v.z; As[lk + 3][lrow] = v.w;
    }
    {
      int gn = n0 + lrow;
      float4 v = {0.f, 0.f, 0.f, 0.f};
      if (gn < N) v = *(const float4*)(B + (long)gn * ldb + (k0 + lk));
      Bs[lk + 0][lrow] = v.x; Bs[lk + 1][lrow] = v.y;
      Bs[lk + 2][lrow] = v.z; Bs[lk + 3][lrow] = v.w;
    }
    __syncthreads();
#pragma unroll
    for (int kk = 0; kk < 16; kk++) {
      float4 a = *(const float4*)&As[kk][ty << 2];
      float4 b = *(const float4*)&Bs[kk][tx << 2];
      acc[0][0] += a.x * b.x; acc[0][1] += a.x * b.y; acc[0][2] += a.x * b.z; acc[0][3] += a.x * b.w;
      acc[1][0] += a.y * b.x; acc[1][1] += a.y * b.y; acc[1][2] += a.y * b.z; acc[1][3] += a.y * b.w;
      acc[2][0] += a.z * b.x; acc[2][1] += a.z * b.y; acc[2][2] += a.z * b.z; acc[2][3] += a.z * b.w;
      acc[3][0] += a.w * b.x; acc[3][1] += a.w * b.y; acc[3][2] += a.w * b.z; acc[3][3] += a.w * b.w;
    }
    __syncthreads();
  }

#pragma unroll
  for (int i = 0; i < 4; i++) {
    int gm = m0 + (ty << 2) + i;
    if (gm >= M) continue;
#pragma unroll
    for (int j = 0; j < 4; j++) {
      int gn = n0 + (tx << 2) + j;
      if (gn >= N) continue;
      float v = acc[i][j];
      if (bias) v += bias[gn];
      C[(long)gm * ldc + gn] = v;
    }
  }
}

// ---------------------------------------------------------------------------
// Softmax: fp32 scores in, bf16 att out (scale folded).
// ---------------------------------------------------------------------------
__global__ __launch_bounds__(256) void mk_softmax(const float* __restrict__ scores,
                                                  ushortt* __restrict__ att, float scale)
{
  int row = (blockIdx.x << 2) + (threadIdx.x >> 6);
  int lane = threadIdx.x & 63;
  const float* p = scores + (long)row * 256 + (lane << 2);
  float4 v = *(const float4*)p;
  float m = fmaxf(fmaxf(v.x, v.y), fmaxf(v.z, v.w));
#pragma unroll
  for (int o = 32; o; o >>= 1) m = fmaxf(m, __shfl_xor(m, o, 64));
  float sl = scale * LOG2E;
  v.x = fexp2(sl * (v.x - m));
  v.y = fexp2(sl * (v.y - m));
  v.z = fexp2(sl * (v.z - m));
  v.w = fexp2(sl * (v.w - m));
  float s = v.x + v.y + v.z + v.w;
#pragma unroll
  for (int o = 32; o; o >>= 1) s += __shfl_xor(s, o, 64);
  float r = 1.f / s;
  ushort4 o4;
  o4.x = f2b(v.x * r); o4.y = f2b(v.y * r); o4.z = f2b(v.z * r); o4.w = f2b(v.w * r);
  *(ushort4*)(att + (long)row * 256 + (lane << 2)) = o4;
}

// ---------------------------------------------------------------------------
__global__ __launch_bounds__(256) void mk_gates(const float* __restrict__ q2,
                                                const float* __restrict__ k2,
                                                float* __restrict__ gacc)
{
  __shared__ float k2p[8 * 808];
  int b = blockIdx.x >> 4, q = blockIdx.x & 15;
  for (int i = threadIdx.x; i < 6144; i += 256) {
    int e = i / 768, rem = i - e * 768;
    int h = rem / 96, j = rem - h * 96;
    k2p[e * 808 + h * 100 + j] = k2[i];
  }
  __syncthreads();
  const float scale = 0.10206207261596577f;
  int wid = threadIdx.x >> 6, lane = threadIdx.x & 63;
  int h = lane >> 3, e = lane & 7;
  const float* kp = &k2p[e * 808 + h * 100];
  float accL = 0.f;
#pragma unroll
  for (int ti = 0; ti < 4; ti++) {
    int l = q * 16 + wid * 4 + ti;
    const float* qh = q2 + ((long)b * LTOK + l) * DIMC + h * 96;
    float sum = 0.f;
#pragma unroll
    for (int j = 0; j < 96; j += 4) {
      float4 qv = *(const float4*)(qh + j);
      float4 kv = *(const float4*)(kp + j);
      sum += qv.x * kv.x + qv.y * kv.y + qv.z * kv.z + qv.w * kv.w;
    }
    float s = sum * scale;
    float mx = s;
#pragma unroll
    for (int o = 1; o <= 4; o <<= 1) mx = fmaxf(mx, __shfl_xor(mx, o, 64));
    float ex = fexp2((s - mx) * LOG2E);
    float se = ex;
#pragma unroll
    for (int o = 1; o <= 4; o <<= 1) se += __shfl_xor(se, o, 64);
    accL += ex / se;
  }
#pragma unroll
  for (int o = 8; o <= 32; o <<= 1) accL += __shfl_xor(accL, o, 64);
  __shared__ float red[4][8];
  if (lane < 8) red[wid][lane] = accL;
  __syncthreads();
  if (threadIdx.x < 8) {
    float v = red[0][threadIdx.x] + red[1][threadIdx.x] +
              red[2][threadIdx.x] + red[3][threadIdx.x];
    atomicAdd(&gacc[b * 8 + threadIdx.x], v);
  }
}

__global__ __launch_bounds__(64) void mk_gatetop(const float* __restrict__ gacc,
                                                 int* __restrict__ pe,
                                                 float* __restrict__ pw)
{
  int b = threadIdx.x;
  if (b >= 16) return;
  float g[8];
  for (int e = 0; e < 8; e++) g[e] = gacc[b * 8 + e] * (1.f / (8.f * 256.f));
  float mx = g[0];
  for (int e = 1; e < 8; e++) mx = fmaxf(mx, g[e]);
  float se = 0.f;
  for (int e = 0; e < 8; e++) { g[e] = expf(g[e] - mx); se += g[e]; }
  for (int e = 0; e < 8; e++) g[e] /= se;
  int i0 = 0;
  for (int e = 1; e < 8; e++) if (g[e] > g[i0]) i0 = e;
  int i1 = (i0 == 0) ? 1 : 0;
  for (int e = 0; e < 8; e++) if (e != i0 && g[e] > g[i1]) i1 = e;
  float w0 = 1.f / (1.f + expf(g[i1] - g[i0]));
  pe[2 * b] = i0; pe[2 * b + 1] = i1;
  pw[2 * b] = w0; pw[2 * b + 1] = 1.f - w0;
}

// ---------------------------------------------------------------------------
__global__ __launch_bounds__(768) void mk_conv(const float* __restrict__ xzx,
                                               const float* __restrict__ cw,
                                               const float* __restrict__ cb,
                                               const int* __restrict__ pe,
                                               float* __restrict__ xc)
{
  int blk = blockIdx.x;
  int p = blk >> 8, t = blk & 255;
  int e = pe[p];
  int h = t >> 4, w = t & 15;
  int c = threadIdx.x;
  const float* wp = cw + ((long)e * DIMC + c) * 9;
  float acc = cb[e * DIMC + c];
#pragma unroll
  for (int dh = 0; dh < 3; dh++) {
    int hh = h + dh - 1;
    if (hh < 0 || hh > 15) continue;
#pragma unroll
    for (int dw = 0; dw < 3; dw++) {
      int ww = w + dw - 1;
      if (ww < 0 || ww > 15) continue;
      acc += xzx[((long)p * LTOK + hh * 16 + ww) * DIMC + c] * wp[dh * 3 + dw];
    }
  }
  xc[((long)p * LTOK + t) * DIMC + c] = acc / (1.f + fexp2(-acc * LOG2E));
}

__device__ __forceinline__ int tmap(int dir, int s) {
  if (dir == 0) return s;
  if (dir == 1) return 255 - s;
  if (dir == 2) return ((s & 15) << 4) | (s >> 4);
  int u = 255 - s;
  return ((u & 15) << 4) | (u >> 4);
}

// ---------------------------------------------------------------------------
// dbl: wave-per-token, lanes on channel dim (coalesced). dblm[p][m][24].
// ---------------------------------------------------------------------------
__global__ __launch_bounds__(256) void mk_dbl(const float* __restrict__ xc,
                                              const float* __restrict__ xproj,
                                              const int* __restrict__ pe,
                                              float* __restrict__ dblm)
{
  int p = blockIdx.x >> 6;
  int tq = blockIdx.x & 63;
  int wid = threadIdx.x >> 6, lane = threadIdx.x & 63;
  int m = tq * 4 + wid;
  int e = pe[p];
  const float* xr = xc + ((long)p * LTOK + m) * DIMC;
  const float* wb = xproj + (long)e * 24 * DIMC;
  float4 xv[3];
#pragma unroll
  for (int j = 0; j < 3; j++) xv[j] = *(const float4*)(xr + j * 256 + lane * 4);
  float acc[24];
#pragma unroll
  for (int r = 0; r < 24; r++) {
    const float* wr = wb + r * DIMC;
    float s = 0.f;
#pragma unroll
    for (int j = 0; j < 3; j++) {
      float4 wv = *(const float4*)(wr + j * 256 + lane * 4);
      s += xv[j].x * wv.x + xv[j].y * wv.y + xv[j].z * wv.z + xv[j].w * wv.w;
    }
    acc[r] = s;
  }
#pragma unroll
  for (int r = 0; r < 24; r++)
#pragma unroll
    for (int o = 32; o; o >>= 1) acc[r] += __shfl_xor(acc[r], o, 64);
  if (lane == 0) {
    float* o = dblm + ((long)p * LTOK + m) * 24;
#pragma unroll
    for (int r = 0; r < 24; r++) o[r] = acc[r];
  }
}

// ---------------------------------------------------------------------------
// Fused segmented scan (unchanged from round 10).
// ---------------------------------------------------------------------------
__global__ __launch_bounds__(512) void mk_scan(const float* __restrict__ xc,
                                               const float* __restrict__ dblm,
                                               const float* __restrict__ dtw,
                                               const float* __restrict__ dtb,
                                               const float* __restrict__ Alog,
                                               const float* __restrict__ Dp,
                                               const int* __restrict__ pe,
                                               float* __restrict__ yac)
{
  __shared__ float dbS[256 * 24];
  __shared__ float yS[256 * 17];
  __shared__ float aS[32][16];
  __shared__ float hS[32][16];
  __shared__ float dsum[16];
  int blk = blockIdx.x;
  int p = blk / 48, cg = blk - p * 48;
  int c0 = cg << 4;
  int e = pe[p];
  int tid = threadIdx.x;
  {
    const float4* src = (const float4*)(dblm + (long)p * LTOK * 24);
    float4* dst = (float4*)dbS;
    for (int i = tid; i < 1536; i += 512) dst[i] = src[i];
  }
  for (int i = tid; i < 256 * 17; i += 512) yS[i] = 0.f;
  if (tid < 16) {
    float s = 0.f;
#pragma unroll
    for (int dd = 0; dd < 4; dd++) s += Dp[(long)(e * 4 + dd) * DIMC + c0 + tid];
    dsum[tid] = s;
  }
  __syncthreads();

  int c = tid & 15;
  int rr = tid >> 4;
  int seg = rr & 7;
  int dir = rr >> 3;
  int d = c0 + c;
  const float* xcp = xc + (long)p * LTOK * DIMC;
  long pb = (long)(e * 4 + dir) * DIMC + d;
  float4 wv = *(const float4*)(dtw + pb * 4);
  float bdt = dtb[pb];
  float Ad = -fexp2(Alog[pb] * LOG2E);
  int t0 = seg << 5;

  float h = 0.f, ap = 1.f;
  for (int tb = 0; tb < 32; tb += 8) {
    float xv[8]; int mm[8];
#pragma unroll
    for (int i = 0; i < 8; i++) {
      mm[i] = tmap(dir, t0 + tb + i);
      xv[i] = xcp[(long)mm[i] * DIMC + d];
    }
#pragma unroll
    for (int i = 0; i < 8; i++) {
      const float* db = &dbS[mm[i] * 24 + dir * 6];
      float xr = wv.x * db[0] + wv.y * db[1] + wv.z * db[2] + wv.w * db[3] + bdt;
      float te = fexp2(xr * LOG2E);
      float g = flog2(1.f + te);
      g = (xr > 60.f) ? xr * LOG2E : g;
      float de = fexp2(g * Ad);
      h = de * h + (g * LN2) * xv[i] * db[4];
      ap *= de;
    }
  }
  aS[rr][c] = ap;
  hS[rr][c] = h;
  __syncthreads();

  float hh = 0.f;
  for (int j = dir * 8; j < rr; j++)
    hh = aS[j][c] * hh + hS[j][c];

  for (int tb = 0; tb < 32; tb += 8) {
    float xv[8]; int mm[8];
#pragma unroll
    for (int i = 0; i < 8; i++) {
      mm[i] = tmap(dir, t0 + tb + i);
      xv[i] = xcp[(long)mm[i] * DIMC + d];
    }
#pragma unroll
    for (int i = 0; i < 8; i++) {
      const float* db = &dbS[mm[i] * 24 + dir * 6];
      float xr = wv.x * db[0] + wv.y * db[1] + wv.z * db[2] + wv.w * db[3] + bdt;
      float te = fexp2(xr * LOG2E);
      float g = flog2(1.f + te);
      g = (xr > 60.f) ? xr * LOG2E : g;
      float de = fexp2(g * Ad);
      hh = de * hh + (g * LN2) * xv[i] * db[4];
      atomicAdd(&yS[mm[i] * 17 + c], hh * db[5]);
    }
  }
  __syncthreads();

  float* yp = yac + (long)p * LTOK * DIMC + c0;
  for (int i = tid; i < 256 * 16; i += 512) {
    int t = i >> 4, cz = i & 15;
    yp[(long)t * DIMC + cz] = yS[t * 17 + cz] + xcp[(long)t * DIMC + c0 + cz] * dsum[cz];
  }
}

// ---------------------------------------------------------------------------
// LN + silu(z) + token partial-mean. 512 blocks = (p, 16-token slice).
// Accumulates into pre-zeroed eo via global atomics; 1/256 applied in mk_out.
// ---------------------------------------------------------------------------
__global__ __launch_bounds__(256) void mk_lnfin(const float* __restrict__ yac,
                                                const float* __restrict__ xzz,
                                                const float* __restrict__ lns,
                                                const float* __restrict__ lnb,
                                                const int* __restrict__ pe,
                                                float* __restrict__ eo)
{
  int blk = blockIdx.x;
  int p = blk >> 4, ts = blk & 15;
  int e = pe[p];
  int tid = threadIdx.x;
  int wid = tid >> 6, lane = tid & 63;
  float ls[12], lb[12], acc[12];
#pragma unroll
  for (int i = 0; i < 12; i++) {
    int d = i * 64 + lane;
    ls[i] = lns[e * DIMC + d];
    lb[i] = lnb[e * DIMC + d];
    acc[i] = 0.f;
  }
#pragma unroll
  for (int tt = 0; tt < 4; tt++) {
    int t = ts * 16 + wid * 4 + tt;
    const float* yr = yac + ((long)p * LTOK + t) * DIMC;
    const float* zr = xzz + ((long)p * LTOK + t) * DIMC;
    float v[12];
    float s = 0.f;
#pragma unroll
    for (int i = 0; i < 12; i++) { v[i] = yr[i * 64 + lane]; s += v[i]; }
#pragma unroll
    for (int o = 32; o; o >>= 1) s += __shfl_xor(s, o, 64);
    float mu = s * (1.f / 768.f);
    float sq = 0.f;
#pragma unroll
    for (int i = 0; i < 12; i++) { float dlt = v[i] - mu; sq += dlt * dlt; }
#pragma unroll
    for (int o = 32; o; o >>= 1) sq += __shfl_xor(sq, o, 64);
    float rs = rsqrtf(sq * (1.f / 768.f) + 1e-5f);
#pragma unroll
    for (int i = 0; i < 12; i++) {
      float y = (v[i] - mu) * rs * ls[i] + lb[i];
      float z = zr[i * 64 + lane];
      y *= z / (1.f + fexp2(-z * LOG2E));
      acc[i] += y;
    }
  }
  __shared__ float sacc[768];
  for (int j = tid; j < 768; j += 256) sacc[j] = 0.f;
  __syncthreads();
#pragma unroll
  for (int i = 0; i < 12; i++) atomicAdd(&sacc[i * 64 + lane], acc[i]);
  __syncthreads();
  for (int j = tid; j < 768; j += 256) atomicAdd(&eo[(long)p * DIMC + j], sacc[j]);
}

__global__ __launch_bounds__(768) void mk_out(const float* __restrict__ eo,
                                              const float* __restrict__ pw,
                                              float* __restrict__ out)
{
  int b = blockIdx.x, d = threadIdx.x;
  float v = pw[2 * b] * eo[(long)(2 * b) * DIMC + d] +
            pw[2 * b + 1] * eo[(long)(2 * b + 1) * DIMC + d];
  out[b * DIMC + d] = v * (1.f / 256.f);
}

// ---------------------------------------------------------------------------
extern "C" void kernel_launch(void* const* d_in, const int* in_sizes, int n_in,
                              void* d_out, int out_size, void* d_ws, size_t ws_size,
                              hipStream_t stream)
{
  const float* x        = (const float*)d_in[0];
  const float* sa_in_w  = (const float*)d_in[1];
  const float* sa_in_b  = (const float*)d_in[2];
  const float* sa_out_w = (const float*)d_in[3];
  const float* sa_out_b = (const float*)d_in[4];
  const float* ca_in_w  = (const float*)d_in[5];
  const float* ca_in_b  = (const float*)d_in[6];
  const float* eq       = (const float*)d_in[7];
  const float* e_in_w   = (const float*)d_in[8];
  const float* e_in_b   = (const float*)d_in[9];
  const float* e_conv_w = (const float*)d_in[10];
  const float* e_conv_b = (const float*)d_in[11];
  const float* e_xproj  = (const float*)d_in[12];
  const float* e_dtw    = (const float*)d_in[13];
  const float* e_dtb    = (const float*)d_in[14];
  const float* e_Alog   = (const float*)d_in[15];
  const float* e_D      = (const float*)d_in[16];
  const float* e_lns    = (const float*)d_in[17];
  const float* e_lnb    = (const float*)d_in[18];
  float* out = (float*)d_out;

  float* ws = (float*)d_ws;
  // ---- attention phase (float offsets) ----
  ushortt* qk_b   = (ushortt*)(ws + 0);          // 4096x1536 bf16  [0 .. 3,145,728)
  float*   scores = ws + 6291456;                // [6,291,456 .. 14,680,064)
  ushortt* dump_b = (ushortt*)(ws + 6291456);    // av dump (scores dead by then)
  ushortt* ctxa_b = (ushortt*)(ws + 7864320);    // 4096x768 bf16 [.. 9,437,184)
  ushortt* att_b  = (ushortt*)(ws + 14680064);   // 16x8x256x256 bf16 [.. 18,874,368)
  ushortt* vt_b   = (ushortt*)(ws + 18874368);   // 128x128x256 bf16 [.. 20,971,520)
  ushortt* xb     = (ushortt*)(ws + 20971520);   // [.. 22,544,384)
  ushortt* wqkv_b = (ushortt*)(ws + 22544384);   // [.. 23,429,120)
  ushortt* saow_b = (ushortt*)(ws + 23429120);   // [.. 23,724,032)
  ushortt* caw_b  = (ushortt*)(ws + 23724032);   // [.. 24,018,944)
  ushortt* ctx_b  = (ushortt*)(ws + 0);          // overlay qk_b (dead post-scores)
  float*   q2     = ws + 1572864;                // [.. 4,718,592) (qk_b dead)
  // ---- persistent smalls ----
  float*   k2     = ws + 25165824;
  int*     pe     = (int*)(ws + 25171968);
  float*   pw     = ws + 25172000;
  float*   eo     = ws + 25172032;               // [.. 25,196,608)
  float*   dblm   = ws + 25196608;               // [.. 25,393,216)
  float*   gacc   = ws + 25393216;               // [.. 25,393,344) peak 101.6MB
  // ---- expert phase ----
  float*   xz_x   = ws + 0;                      // [.. 6,291,456)
  float*   xz_z   = ws + 6291456;                // [.. 12,582,912) live -> lnfin
  ushortt* ew_b   = (ushortt*)(ws + 12582912);   // [.. 17,301,504) (scores/att dead)
  float*   xc     = ws + 12582912;               // [.. 18,874,368) after ew_b dead
  float*   yac    = ws + 18874368;               // [.. 25,165,824)

  const float scale = 0.10206207261596577f;

  // 0. fused upfront casts: x, sa_in_w, sa_out_w, ca_in_w[:768]
  mk_mcast4<<<5952, 256, 0, stream>>>(x, xb, sa_in_w, wqkv_b, sa_out_w, saow_b,
                                      ca_in_w, caw_b);
  // 1. qkv MFMA: q,k -> qk_b bf16 (ld 1536); v -> vt_b transposed bf16
  mk_mfma<<<dim3(576, 1), 256, 0, stream>>>(xb, wqkv_b, sa_in_b, qk_b,
      768, 768, 768, 1536, 1, 0, 0, 0, 0, 0, 0, 0, nullptr, 18,
      1, 1536, vt_b, 0, 1, 1);
  // 2. scores = q @ k^T  (bf16 MFMA, K=96, Z=128, fp32 out)
  mk_mfma<<<dim3(4, 128), 256, 0, stream>>>(qk_b, qk_b + 768, nullptr, scores,
      96, 1536, 1536, 256, 8, 393216, 96, 393216, 96, 524288, 65536, 0, nullptr, 2,
      0, 1 << 30, nullptr, 0, 0, 0);
  // 3. softmax -> att_b bf16
  mk_softmax<<<8192, 256, 0, stream>>>(scores, att_b, scale);
  // 4. ctxa = att @ v  (bf16 MFMA via vt, N=96 + dump, Z=128)
  mk_mfma<<<dim3(2, 128), 256, 0, stream>>>(att_b, vt_b, nullptr, ctxa_b,
      256, 256, 256, 768, 8, 524288, 65536, 262144, 32768, 196608, 96, 0, nullptr, 1,
      1, 96, dump_b, 32, 1, 0);
  // 4b. cast expert weights (scores/att regions dead)
  mk_cast<<<9216, 256, 0, stream>>>(e_in_w, ew_b, 9437184);
  // 5. ctx = ctxa @ sa_out_w^T + b -> bf16
  mk_mfma<<<dim3(192, 1), 256, 0, stream>>>(ctxa_b, saow_b, sa_out_b, ctx_b,
      768, 768, 768, 768, 1, 0, 0, 0, 0, 0, 0, 0, nullptr, 6,
      1, 1 << 30, nullptr, 0, 0, 0);
  // 6. q2 = ctx @ ca_in_w[:768]^T + b (fp32 out)
  mk_mfma<<<dim3(192, 1), 256, 0, stream>>>(ctx_b, caw_b, ca_in_b, q2,
      768, 768, 768, 768, 1, 0, 0, 0, 0, 0, 0, 0, nullptr, 6,
      0, 1 << 30, nullptr, 0, 0, 0);
  // 7. k2 = eq @ ca_in_w[768:]^T + b  (8x768x768 fp32)
  mk_gemm<<<dim3(12, 1), 256, 0, stream>>>(eq, ca_in_w + 589824, ca_in_b + 768, k2,
      8, 768, 768, 768, 768, 768, 12);
  // 8. gate
  (void)hipMemsetAsync(gacc, 0, 128 * sizeof(float), stream);
  (void)hipMemsetAsync(eo, 0, 24576 * sizeof(float), stream);
  mk_gates<<<256, 256, 0, stream>>>(q2, k2, gacc);
  mk_gatetop<<<1, 64, 0, stream>>>(gacc, pe, pw);
  // 9. xz = x @ e_in_w[e]^T + b (Z=32 pair mode) split -> xz_x | xz_z
  mk_mfma<<<dim3(24, 32), 256, 0, stream>>>(xb, ew_b, e_in_b, xz_x,
      768, 768, 768, 768, 1, 196608, 0, 1179648, 0, 196608, 0, 1536, pe, 12,
      0, 768, xz_z, 768, 0, 0);
  // 10. depthwise conv + SiLU
  mk_conv<<<32 * 256, 768, 0, stream>>>(xz_x, e_conv_w, e_conv_b, pe, xc);
  // 11. dbl projections
  mk_dbl<<<2048, 256, 0, stream>>>(xc, e_xproj, pe, dblm);
  // 12. fused segmented scan
  mk_scan<<<1536, 512, 0, stream>>>(xc, dblm, e_dtw, e_dtb, e_Alog, e_D, pe, yac);
  // 13. LN + silu(z) + token mean (512 blocks, atomic into eo)
  mk_lnfin<<<512, 256, 0, stream>>>(yac, xz_z, e_lns, e_lnb, pe, eo);
  // 14. weighted top-2 combine (1/256 folded)
  mk_out<<<16, 768, 0, stream>>>(eo, pw, out);

  (void)in_sizes; (void)n_in; (void)out_size; (void)ws_size;
}